// Round 2
// baseline (414.677 us; speedup 1.0000x reference)
//
#include <hip/hip_runtime.h>
#include <hip/hip_bf16.h>

// Problem constants (INPUT_SIZE=256, IN_CH=OUT_CH=1536, B=8)
//   x0: [8, 512, 32, 32] f32     (4,194,304 elems)
//   x1: [8, 1024, 16, 16] f32    (2,097,152 elems)
//   W : [1536, 1536] f32, b: [1536] f32
//   out: [8192, 1536] f32
//
// Math folding:
//   X[n, o<768]   = (1/6)  * sum_{f=6o..6o+5}   x0pad[b, f/9, h+(f%9)/3-1, w+f%3-1]
//   X[n, 768+m]   = bilinear_up( q1[b, :, :, m] ) at (h,w), align_corners=False (clamped taps)
//   q1[b,sh,sw,m] = (1/12) * sum_{f=12m..12m+11} x1pad[b, f/9, sh+(f%9)/3-1, sw+f%3-1]
//   out = X @ W^T + b   (bf16 MFMA, fp32 accum)

typedef __bf16 bf16x8 __attribute__((ext_vector_type(8)));
typedef float  f32x4  __attribute__((ext_vector_type(4)));
typedef const void __attribute__((address_space(1)))* gptr_t;
typedef void __attribute__((address_space(3)))* sptr_t;

#define M_TOT 8192
#define N_TOT 1536
#define K_TOT 1536

// ---------------- W -> bf16 (2,359,296 elems, exact grid) ----------------
__global__ void wcvt_kernel(const float* __restrict__ W, __hip_bfloat16* __restrict__ Wb) {
  int i = (blockIdx.x * blockDim.x + threadIdx.x) * 4;
  float4 v = *(const float4*)(W + i);
  Wb[i + 0] = __float2bfloat16(v.x);
  Wb[i + 1] = __float2bfloat16(v.y);
  Wb[i + 2] = __float2bfloat16(v.z);
  Wb[i + 3] = __float2bfloat16(v.w);
}

// ---------------- q1 pool: [8][16][16][768] f32, exact grid ----------------
__global__ void feat1_pool_kernel(const float* __restrict__ x1, float* __restrict__ q1) {
  int idx = blockIdx.x * blockDim.x + threadIdx.x;   // 8*16*16*768 = 1,572,864
  int m = idx % 768;
  int t = idx / 768;
  int sw = t & 15; t >>= 4;
  int sh = t & 15; int b = t >> 4;

  int c = (4 * m) / 3;          // 12m / 9
  int r = 3 * (m % 3);          // 12m mod 9
  float s = 0.f;
#pragma unroll
  for (int i = 0; i < 12; ++i) {
    int ki = r / 3, kj = r - 3 * (r / 3);
    int y = sh + ki - 1, x = sw + kj - 1;
    if (y >= 0 && y < 16 && x >= 0 && x < 16)
      s += x1[((b * 1024 + c) * 16 + y) * 16 + x];
    if (++r == 9) { r = 0; ++c; }
  }
  q1[idx] = s * (1.f / 12.f);
}

// ---------------- X build: bf16 [8192][1536], exact grid ----------------
__global__ void feat_build_kernel(const float* __restrict__ x0, const float* __restrict__ q1,
                                  __hip_bfloat16* __restrict__ X) {
  int idx = blockIdx.x * blockDim.x + threadIdx.x;   // 12,582,912
  int o = idx % 1536;
  int n = idx / 1536;
  int w = n & 31, h = (n >> 5) & 31, b = n >> 10;

  float val;
  if (o < 768) {
    int c = (2 * o) / 3;        // 6o / 9
    int r = 3 * ((2 * o) % 3);  // 6o mod 9
    float s = 0.f;
#pragma unroll
    for (int i = 0; i < 6; ++i) {
      int ki = r / 3, kj = r - 3 * (r / 3);
      int y = h + ki - 1, x = w + kj - 1;
      if (y >= 0 && y < 32 && x >= 0 && x < 32)
        s += x0[((b * 512 + c) * 32 + y) * 32 + x];
      if (++r == 9) { r = 0; ++c; }
    }
    val = s * (1.f / 6.f);
  } else {
    int m = o - 768;
    // align_corners=False, scale 2: src = h/2 - 0.25 ; edge renorm == clamp
    int th = h >> 1, tw = w >> 1;
    int i0, i1, j0, j1;
    float wh0, wh1, wv0, wv1;
    if ((h & 1) == 0) { i0 = th - 1; i1 = th; wh0 = 0.25f; wh1 = 0.75f; }
    else              { i0 = th; i1 = th + 1; wh0 = 0.75f; wh1 = 0.25f; }
    if ((w & 1) == 0) { j0 = tw - 1; j1 = tw; wv0 = 0.25f; wv1 = 0.75f; }
    else              { j0 = tw; j1 = tw + 1; wv0 = 0.75f; wv1 = 0.25f; }
    if (i0 < 0) i0 = 0; if (i1 > 15) i1 = 15;
    if (j0 < 0) j0 = 0; if (j1 > 15) j1 = 15;
    const float* q = q1 + (size_t)b * (16 * 16 * 768) + m;
    float s00 = q[(i0 * 16 + j0) * 768];
    float s01 = q[(i0 * 16 + j1) * 768];
    float s10 = q[(i1 * 16 + j0) * 768];
    float s11 = q[(i1 * 16 + j1) * 768];
    val = wh0 * (wv0 * s00 + wv1 * s01) + wh1 * (wv0 * s10 + wv1 * s11);
  }
  X[idx] = __float2bfloat16(val);
}

// ---------------- GEMM: out[M][N] = X[M][K] * Wb[N][K]^T + bias ----------------
// m97 structure: 128x128 tile, BK=64, 4 waves (2x2 of 64x64), 16x16x32 MFMA,
// linear LDS + global_load_lds width 16, XCD-aware block swizzle.
#define TM 128
#define TN 128
#define TK 64

__global__ __launch_bounds__(256) void gemm_kernel(
    const __hip_bfloat16* __restrict__ X,
    const __hip_bfloat16* __restrict__ Wb,
    const float* __restrict__ bias,
    float* __restrict__ out) {
  __shared__ __align__(16) __hip_bfloat16 As[TM * TK];
  __shared__ __align__(16) __hip_bfloat16 Bs[TN * TK];

  const int tid = threadIdx.x;
  const int lane = tid & 63;
  const int wave = tid >> 6;
  const int wr = wave >> 1, wc = wave & 1;

  // XCD-aware bijective swizzle: 768 blocks = 8 * 96
  int id = blockIdx.y * gridDim.x + blockIdx.x;
  int swz = (id & 7) * 96 + (id >> 3);
  const int tileN = (swz % 12) * TN;
  const int tileM = (swz / 12) * TM;

  f32x4 acc[4][4] = {};

  for (int k0 = 0; k0 < K_TOT; k0 += TK) {
    // stage A tile: 128x64 bf16 = 16KB ; 256 thr * 4 issues * 16B
#pragma unroll
    for (int i = 0; i < 4; ++i) {
      int e = i * 2048 + tid * 8;      // bf16 element offset in tile
      int row = e >> 6, col = e & 63;
      __builtin_amdgcn_global_load_lds(
          (gptr_t)(X + (size_t)(tileM + row) * K_TOT + k0 + col),
          (sptr_t)(&As[e]), 16, 0, 0);
    }
#pragma unroll
    for (int i = 0; i < 4; ++i) {
      int e = i * 2048 + tid * 8;
      int row = e >> 6, col = e & 63;
      __builtin_amdgcn_global_load_lds(
          (gptr_t)(Wb + (size_t)(tileN + row) * K_TOT + k0 + col),
          (sptr_t)(&Bs[e]), 16, 0, 0);
    }
    asm volatile("s_waitcnt vmcnt(0)" ::: "memory");
    __syncthreads();

#pragma unroll
    for (int kk = 0; kk < TK; kk += 32) {
      bf16x8 afr[4], bfr[4];
      int kof = kk + ((lane >> 4) << 3);
#pragma unroll
      for (int mf = 0; mf < 4; ++mf) {
        int row = wr * 64 + mf * 16 + (lane & 15);
        afr[mf] = *(const bf16x8*)(&As[row * TK + kof]);
      }
#pragma unroll
      for (int nf = 0; nf < 4; ++nf) {
        int col = wc * 64 + nf * 16 + (lane & 15);
        bfr[nf] = *(const bf16x8*)(&Bs[col * TK + kof]);
      }
#pragma unroll
      for (int mf = 0; mf < 4; ++mf)
#pragma unroll
        for (int nf = 0; nf < 4; ++nf)
          acc[mf][nf] = __builtin_amdgcn_mfma_f32_16x16x32_bf16(
              afr[mf], bfr[nf], acc[mf][nf], 0, 0, 0);
    }
    __syncthreads();
  }

  // epilogue: D layout col = lane&15, row = (lane>>4)*4 + reg   [m89-verified]
  const int colbase = tileN + wc * 64 + (lane & 15);
  const int rowbase = tileM + wr * 64 + ((lane >> 4) << 2);
#pragma unroll
  for (int mf = 0; mf < 4; ++mf) {
#pragma unroll
    for (int nf = 0; nf < 4; ++nf) {
      int col = colbase + nf * 16;
      float bv = bias[col];
#pragma unroll
      for (int r = 0; r < 4; ++r) {
        int row = rowbase + mf * 16 + r;
        out[(size_t)row * N_TOT + col] = acc[mf][nf][r] + bv;
      }
    }
  }
}

extern "C" void kernel_launch(void* const* d_in, const int* in_sizes, int n_in,
                              void* d_out, int out_size, void* d_ws, size_t ws_size,
                              hipStream_t stream) {
  const float* x0 = (const float*)d_in[0];
  const float* x1 = (const float*)d_in[1];
  const float* W = (const float*)d_in[2];
  const float* bias = (const float*)d_in[3];
  float* out = (float*)d_out;

  char* ws = (char*)d_ws;
  __hip_bfloat16* X = (__hip_bfloat16*)ws;                        // 25,165,824 B
  __hip_bfloat16* Wb = (__hip_bfloat16*)(ws + 25165824);          //  4,718,592 B
  float* q1 = (float*)(ws + 25165824 + 4718592);                  //  6,291,456 B

  wcvt_kernel<<<2359296 / 4 / 256, 256, 0, stream>>>(W, Wb);
  feat1_pool_kernel<<<1572864 / 256, 256, 0, stream>>>(x1, q1);
  feat_build_kernel<<<12582912 / 256, 256, 0, stream>>>(x0, q1, X);

  dim3 grid(N_TOT / TN, M_TOT / TM);  // (12, 64) = 768 blocks
  gemm_kernel<<<grid, 256, 0, stream>>>(X, Wb, bias, out);
}

// Round 3
// 212.117 us; speedup vs baseline: 1.9549x; 1.9549x over previous
//
#include <hip/hip_runtime.h>
#include <hip/hip_bf16.h>

// Problem constants (INPUT_SIZE=256, IN_CH=OUT_CH=1536, B=8)
//   x0: [8, 512, 32, 32] f32;  x1: [8, 1024, 16, 16] f32
//   W : [1536, 1536] f32, b: [1536] f32;  out: [8192, 1536] f32
//
// Row-sum folding (T = horizontal 3-tap sum of a padded row):
//   o=3t  : X = (T[2t,  h-1] + T[2t,  h  ])/6
//   o=3t+1: X = (T[2t,  h+1] + T[2t+1,h-1])/6
//   o=3t+2: X = (T[2t+1,h  ] + T[2t+1,h+1])/6
//   m=3t  : q1 = (T1[4t,  all3] + T1[4t+1,sh-1])/12
//   m=3t+1: q1 = (T1[4t+1,sh..] + T1[4t+2,sh-1..sh])/12
//   m=3t+2: q1 = (T1[4t+2,sh+1] + T1[4t+3,all3])/12
//   X[:,768+m] = bilinear_up(q1), align_corners=False == clamped 4-tap
//   out = X @ W^T + b   (bf16 MFMA, fp32 accum)

typedef __bf16 bf16x8 __attribute__((ext_vector_type(8)));
typedef float  f32x4  __attribute__((ext_vector_type(4)));
typedef const void __attribute__((address_space(1)))* gptr_t;
typedef void __attribute__((address_space(3)))* sptr_t;

#define M_TOT 8192
#define N_TOT 1536
#define K_TOT 1536

// ---------------- W -> bf16 ----------------
__global__ void wcvt_kernel(const float* __restrict__ W, __hip_bfloat16* __restrict__ Wb) {
  int i = (blockIdx.x * blockDim.x + threadIdx.x) * 4;
  float4 v = *(const float4*)(W + i);
  Wb[i + 0] = __float2bfloat16(v.x);
  Wb[i + 1] = __float2bfloat16(v.y);
  Wb[i + 2] = __float2bfloat16(v.z);
  Wb[i + 3] = __float2bfloat16(v.w);
}

// ---------------- feat0: X[:, 0:768] via LDS row-sums ----------------
// block = (cb, h, b); 64 channels -> 96 outputs; 256 threads
__global__ __launch_bounds__(256) void feat0_kernel(const float* __restrict__ x0,
                                                    __hip_bfloat16* __restrict__ X) {
  __shared__ float T[64 * 3 * 32];                       // [c][y][w] 24 KB
  __shared__ __align__(16) unsigned short outT[32 * 100]; // [n=w][o] pad->100, 6.4 KB
  const int cb = blockIdx.x, h = blockIdx.y, b = blockIdx.z;
  const int tid = threadIdx.x;
  const float* xb = x0 + (size_t)(b * 512 + cb * 64) * 1024;

  // phase 1: 6144 T values, coalesced row reads
#pragma unroll
  for (int i = 0; i < 24; ++i) {
    int v = tid + i * 256;
    int c = v / 96, rem = v - c * 96;
    int y = rem >> 5, w = rem & 31;
    int gy = h + y - 1;
    float s = 0.f;
    if (gy >= 0 && gy < 32) {
      const float* row = xb + (c * 32 + gy) * 32;
      s = row[w];
      if (w > 0)  s += row[w - 1];
      if (w < 31) s += row[w + 1];
    }
    T[v] = s;
  }
  __syncthreads();

  // phase 2: 12 outputs/thread, 2 LDS reads each (conflict-free: w stride-1)
  const int w = tid & 31, og = tid >> 5;
#pragma unroll
  for (int k = 0; k < 12; ++k) {
    int ol = og * 12 + k;
    int tl = ol / 3, p = ol - 3 * tl;
    const float* Tb = T + (2 * tl) * 96;
    float s;
    if (p == 0)      s = Tb[w]       + Tb[32 + w];
    else if (p == 1) s = Tb[64 + w]  + Tb[96 + w];
    else             s = Tb[128 + w] + Tb[160 + w];
    __hip_bfloat16 hv = __float2bfloat16(s * (1.f / 6.f));
    outT[w * 100 + ol] = *(unsigned short*)&hv;
  }
  __syncthreads();

  // phase 3: coalesced write, 768 ushort4 chunks
#pragma unroll
  for (int i = 0; i < 3; ++i) {
    int q = tid + i * 256;
    int nl = q / 24, qc = q - nl * 24;
    ushort4 v4 = *(const ushort4*)&outT[nl * 100 + qc * 4];
    *(ushort4*)&X[(size_t)(b * 1024 + h * 32 + nl) * 1536 + cb * 96 + qc * 4] = v4;
  }
}

// ---------------- feat1: q1[b][sh][sw][m] via LDS row-sums ----------------
// block = (cb, sh, b); 128 channels -> 96 m; 256 threads
__global__ __launch_bounds__(256) void feat1_kernel(const float* __restrict__ x1,
                                                    float* __restrict__ q1) {
  __shared__ float T[128 * 3 * 16];                   // [c][y][sw] 24 KB
  __shared__ __align__(16) float outT[16 * 100];      // [sw][m] pad->100, 6.4 KB
  const int cb = blockIdx.x, sh = blockIdx.y, b = blockIdx.z;
  const int tid = threadIdx.x;
  const float* xb = x1 + (size_t)(b * 1024 + cb * 128) * 256;

#pragma unroll
  for (int i = 0; i < 24; ++i) {
    int v = tid + i * 256;
    int c = v / 48, rem = v - c * 48;
    int y = rem >> 4, w = rem & 15;
    int gy = sh + y - 1;
    float s = 0.f;
    if (gy >= 0 && gy < 16) {
      const float* row = xb + (c * 16 + gy) * 16;
      s = row[w];
      if (w > 0)  s += row[w - 1];
      if (w < 15) s += row[w + 1];
    }
    T[v] = s;
  }
  __syncthreads();

  const int w = tid & 15, mg = tid >> 4;
#pragma unroll
  for (int k = 0; k < 6; ++k) {
    int ml = mg * 6 + k;
    int tl = ml / 3, p = ml - 3 * tl;
    const float* Tb = T + (4 * tl) * 48;
    float s;
    if (p == 0)      s = Tb[w]       + Tb[16 + w]  + Tb[32 + w]  + Tb[48 + w];
    else if (p == 1) s = Tb[64 + w]  + Tb[80 + w]  + Tb[96 + w]  + Tb[112 + w];
    else             s = Tb[128 + w] + Tb[144 + w] + Tb[160 + w] + Tb[176 + w];
    outT[w * 100 + ml] = s * (1.f / 12.f);
  }
  __syncthreads();

  // 16 rows x 24 float4 chunks = 384
#pragma unroll
  for (int i = 0; i < 2; ++i) {
    int q = tid + i * 256;
    if (q < 384) {
      int nl = q / 24, qc = q - nl * 24;
      float4 v4 = *(const float4*)&outT[nl * 100 + qc * 4];
      *(float4*)&q1[(size_t)(b * 256 + sh * 16 + nl) * 768 + cb * 96 + qc * 4] = v4;
    }
  }
}

// ---------------- feat1up: bilinear 16->32, X[:, 768:1536] ----------------
__global__ __launch_bounds__(256) void feat1up_kernel(const float* __restrict__ q1,
                                                      __hip_bfloat16* __restrict__ X) {
  int idx = blockIdx.x * blockDim.x + threadIdx.x;   // 8192 * 192
  int mg = idx % 192;
  int n = idx / 192;
  int w = n & 31, h = (n >> 5) & 31, b = n >> 10;

  int th = h >> 1, tw = w >> 1;
  int i0, i1, j0, j1;
  float wh0, wh1, wv0, wv1;
  if ((h & 1) == 0) { i0 = th - 1; i1 = th;     wh0 = 0.25f; wh1 = 0.75f; }
  else              { i0 = th;     i1 = th + 1; wh0 = 0.75f; wh1 = 0.25f; }
  if ((w & 1) == 0) { j0 = tw - 1; j1 = tw;     wv0 = 0.25f; wv1 = 0.75f; }
  else              { j0 = tw;     j1 = tw + 1; wv0 = 0.75f; wv1 = 0.25f; }
  if (i0 < 0) i0 = 0; if (i1 > 15) i1 = 15;
  if (j0 < 0) j0 = 0; if (j1 > 15) j1 = 15;

  const float* q = q1 + (size_t)b * 196608 + mg * 4;
  float4 s00 = *(const float4*)&q[(i0 * 16 + j0) * 768];
  float4 s01 = *(const float4*)&q[(i0 * 16 + j1) * 768];
  float4 s10 = *(const float4*)&q[(i1 * 16 + j0) * 768];
  float4 s11 = *(const float4*)&q[(i1 * 16 + j1) * 768];

  float4 v;
  v.x = wh0 * (wv0 * s00.x + wv1 * s01.x) + wh1 * (wv0 * s10.x + wv1 * s11.x);
  v.y = wh0 * (wv0 * s00.y + wv1 * s01.y) + wh1 * (wv0 * s10.y + wv1 * s11.y);
  v.z = wh0 * (wv0 * s00.z + wv1 * s01.z) + wh1 * (wv0 * s10.z + wv1 * s11.z);
  v.w = wh0 * (wv0 * s00.w + wv1 * s01.w) + wh1 * (wv0 * s10.w + wv1 * s11.w);

  ushort4 o;
  __hip_bfloat16 t0 = __float2bfloat16(v.x); o.x = *(unsigned short*)&t0;
  __hip_bfloat16 t1 = __float2bfloat16(v.y); o.y = *(unsigned short*)&t1;
  __hip_bfloat16 t2 = __float2bfloat16(v.z); o.z = *(unsigned short*)&t2;
  __hip_bfloat16 t3 = __float2bfloat16(v.w); o.w = *(unsigned short*)&t3;
  *(ushort4*)&X[(size_t)n * 1536 + 768 + mg * 4] = o;
}

// ---------------- GEMM: out[M][N] = X[M][K] * Wb[N][K]^T + bias ----------------
#define TM 128
#define TN 128
#define TK 64

__global__ __launch_bounds__(256) void gemm_kernel(
    const __hip_bfloat16* __restrict__ X,
    const __hip_bfloat16* __restrict__ Wb,
    const float* __restrict__ bias,
    float* __restrict__ out) {
  __shared__ __align__(16) __hip_bfloat16 As[TM * TK];
  __shared__ __align__(16) __hip_bfloat16 Bs[TN * TK];

  const int tid = threadIdx.x;
  const int lane = tid & 63;
  const int wave = tid >> 6;
  const int wr = wave >> 1, wc = wave & 1;

  int id = blockIdx.y * gridDim.x + blockIdx.x;
  int swz = (id & 7) * 96 + (id >> 3);
  const int tileN = (swz % 12) * TN;
  const int tileM = (swz / 12) * TM;

  f32x4 acc[4][4] = {};

  for (int k0 = 0; k0 < K_TOT; k0 += TK) {
#pragma unroll
    for (int i = 0; i < 4; ++i) {
      int e = i * 2048 + tid * 8;
      int row = e >> 6, col = e & 63;
      __builtin_amdgcn_global_load_lds(
          (gptr_t)(X + (size_t)(tileM + row) * K_TOT + k0 + col),
          (sptr_t)(&As[e]), 16, 0, 0);
    }
#pragma unroll
    for (int i = 0; i < 4; ++i) {
      int e = i * 2048 + tid * 8;
      int row = e >> 6, col = e & 63;
      __builtin_amdgcn_global_load_lds(
          (gptr_t)(Wb + (size_t)(tileN + row) * K_TOT + k0 + col),
          (sptr_t)(&Bs[e]), 16, 0, 0);
    }
    asm volatile("s_waitcnt vmcnt(0)" ::: "memory");
    __syncthreads();

#pragma unroll
    for (int kk = 0; kk < TK; kk += 32) {
      bf16x8 afr[4], bfr[4];
      int kof = kk + ((lane >> 4) << 3);
#pragma unroll
      for (int mf = 0; mf < 4; ++mf) {
        int row = wr * 64 + mf * 16 + (lane & 15);
        afr[mf] = *(const bf16x8*)(&As[row * TK + kof]);
      }
#pragma unroll
      for (int nf = 0; nf < 4; ++nf) {
        int col = wc * 64 + nf * 16 + (lane & 15);
        bfr[nf] = *(const bf16x8*)(&Bs[col * TK + kof]);
      }
#pragma unroll
      for (int mf = 0; mf < 4; ++mf)
#pragma unroll
        for (int nf = 0; nf < 4; ++nf)
          acc[mf][nf] = __builtin_amdgcn_mfma_f32_16x16x32_bf16(
              afr[mf], bfr[nf], acc[mf][nf], 0, 0, 0);
    }
    __syncthreads();
  }

  const int colbase = tileN + wc * 64 + (lane & 15);
  const int rowbase = tileM + wr * 64 + ((lane >> 4) << 2);
#pragma unroll
  for (int mf = 0; mf < 4; ++mf) {
#pragma unroll
    for (int nf = 0; nf < 4; ++nf) {
      int col = colbase + nf * 16;
      float bv = bias[col];
#pragma unroll
      for (int r = 0; r < 4; ++r) {
        int row = rowbase + mf * 16 + r;
        out[(size_t)row * N_TOT + col] = acc[mf][nf][r] + bv;
      }
    }
  }
}

extern "C" void kernel_launch(void* const* d_in, const int* in_sizes, int n_in,
                              void* d_out, int out_size, void* d_ws, size_t ws_size,
                              hipStream_t stream) {
  const float* x0 = (const float*)d_in[0];
  const float* x1 = (const float*)d_in[1];
  const float* W = (const float*)d_in[2];
  const float* bias = (const float*)d_in[3];
  float* out = (float*)d_out;

  char* ws = (char*)d_ws;
  __hip_bfloat16* X = (__hip_bfloat16*)ws;                        // 25,165,824 B
  __hip_bfloat16* Wb = (__hip_bfloat16*)(ws + 25165824);          //  4,718,592 B
  float* q1 = (float*)(ws + 25165824 + 4718592);                  //  6,291,456 B

  wcvt_kernel<<<2359296 / 4 / 256, 256, 0, stream>>>(W, Wb);
  feat1_kernel<<<dim3(8, 16, 8), 256, 0, stream>>>(x1, q1);
  feat0_kernel<<<dim3(8, 32, 8), 256, 0, stream>>>(x0, X);
  feat1up_kernel<<<1572864 / 256, 256, 0, stream>>>(q1, X);

  dim3 grid(N_TOT / TN, M_TOT / TM);  // (12, 64) = 768 blocks
  gemm_kernel<<<grid, 256, 0, stream>>>(X, Wb, bias, out);
}

// Round 4
// 195.276 us; speedup vs baseline: 2.1235x; 1.0862x over previous
//
#include <hip/hip_runtime.h>
#include <hip/hip_bf16.h>

// Problem constants (INPUT_SIZE=256, IN_CH=OUT_CH=1536, B=8)
//   x0: [8, 512, 32, 32] f32;  x1: [8, 1024, 16, 16] f32
//   W : [1536, 1536] f32, b: [1536] f32;  out: [8192, 1536] f32

typedef __bf16 bf16x8 __attribute__((ext_vector_type(8)));
typedef float  f32x4  __attribute__((ext_vector_type(4)));
typedef const void __attribute__((address_space(1)))* gptr_t;
typedef void __attribute__((address_space(3)))* sptr_t;

#define M_TOT 8192
#define N_TOT 1536
#define K_TOT 1536

// ---------------- W -> bf16 ----------------
__global__ void wcvt_kernel(const float* __restrict__ W, __hip_bfloat16* __restrict__ Wb) {
  int i = (blockIdx.x * blockDim.x + threadIdx.x) * 4;
  float4 v = *(const float4*)(W + i);
  Wb[i + 0] = __float2bfloat16(v.x);
  Wb[i + 1] = __float2bfloat16(v.y);
  Wb[i + 2] = __float2bfloat16(v.z);
  Wb[i + 3] = __float2bfloat16(v.w);
}

// ---------------- feat0: X[:, 0:768] via LDS row-sums ----------------
__global__ __launch_bounds__(256) void feat0_kernel(const float* __restrict__ x0,
                                                    __hip_bfloat16* __restrict__ X) {
  __shared__ float T[64 * 3 * 32];
  __shared__ __align__(16) unsigned short outT[32 * 100];
  const int cb = blockIdx.x, h = blockIdx.y, b = blockIdx.z;
  const int tid = threadIdx.x;
  const float* xb = x0 + (size_t)(b * 512 + cb * 64) * 1024;

#pragma unroll
  for (int i = 0; i < 24; ++i) {
    int v = tid + i * 256;
    int c = v / 96, rem = v - c * 96;
    int y = rem >> 5, w = rem & 31;
    int gy = h + y - 1;
    float s = 0.f;
    if (gy >= 0 && gy < 32) {
      const float* row = xb + (c * 32 + gy) * 32;
      s = row[w];
      if (w > 0)  s += row[w - 1];
      if (w < 31) s += row[w + 1];
    }
    T[v] = s;
  }
  __syncthreads();

  const int w = tid & 31, og = tid >> 5;
#pragma unroll
  for (int k = 0; k < 12; ++k) {
    int ol = og * 12 + k;
    int tl = ol / 3, p = ol - 3 * tl;
    const float* Tb = T + (2 * tl) * 96;
    float s;
    if (p == 0)      s = Tb[w]       + Tb[32 + w];
    else if (p == 1) s = Tb[64 + w]  + Tb[96 + w];
    else             s = Tb[128 + w] + Tb[160 + w];
    __hip_bfloat16 hv = __float2bfloat16(s * (1.f / 6.f));
    outT[w * 100 + ol] = *(unsigned short*)&hv;
  }
  __syncthreads();

#pragma unroll
  for (int i = 0; i < 3; ++i) {
    int q = tid + i * 256;
    int nl = q / 24, qc = q - nl * 24;
    ushort4 v4 = *(const ushort4*)&outT[nl * 100 + qc * 4];
    *(ushort4*)&X[(size_t)(b * 1024 + h * 32 + nl) * 1536 + cb * 96 + qc * 4] = v4;
  }
}

// ---------------- feat1: q1[b][sh][sw][m] via LDS row-sums ----------------
__global__ __launch_bounds__(256) void feat1_kernel(const float* __restrict__ x1,
                                                    float* __restrict__ q1) {
  __shared__ float T[128 * 3 * 16];
  __shared__ __align__(16) float outT[16 * 100];
  const int cb = blockIdx.x, sh = blockIdx.y, b = blockIdx.z;
  const int tid = threadIdx.x;
  const float* xb = x1 + (size_t)(b * 1024 + cb * 128) * 256;

#pragma unroll
  for (int i = 0; i < 24; ++i) {
    int v = tid + i * 256;
    int c = v / 48, rem = v - c * 48;
    int y = rem >> 4, w = rem & 15;
    int gy = sh + y - 1;
    float s = 0.f;
    if (gy >= 0 && gy < 16) {
      const float* row = xb + (c * 16 + gy) * 16;
      s = row[w];
      if (w > 0)  s += row[w - 1];
      if (w < 15) s += row[w + 1];
    }
    T[v] = s;
  }
  __syncthreads();

  const int w = tid & 15, mg = tid >> 4;
#pragma unroll
  for (int k = 0; k < 6; ++k) {
    int ml = mg * 6 + k;
    int tl = ml / 3, p = ml - 3 * tl;
    const float* Tb = T + (4 * tl) * 48;
    float s;
    if (p == 0)      s = Tb[w]       + Tb[16 + w]  + Tb[32 + w]  + Tb[48 + w];
    else if (p == 1) s = Tb[64 + w]  + Tb[80 + w]  + Tb[96 + w]  + Tb[112 + w];
    else             s = Tb[128 + w] + Tb[144 + w] + Tb[160 + w] + Tb[176 + w];
    outT[w * 100 + ml] = s * (1.f / 12.f);
  }
  __syncthreads();

#pragma unroll
  for (int i = 0; i < 2; ++i) {
    int q = tid + i * 256;
    if (q < 384) {
      int nl = q / 24, qc = q - nl * 24;
      float4 v4 = *(const float4*)&outT[nl * 100 + qc * 4];
      *(float4*)&q1[(size_t)(b * 256 + sh * 16 + nl) * 768 + cb * 96 + qc * 4] = v4;
    }
  }
}

// ---------------- feat1up: bilinear 16->32, X[:, 768:1536] ----------------
__global__ __launch_bounds__(256) void feat1up_kernel(const float* __restrict__ q1,
                                                      __hip_bfloat16* __restrict__ X) {
  int idx = blockIdx.x * blockDim.x + threadIdx.x;
  int mg = idx % 192;
  int n = idx / 192;
  int w = n & 31, h = (n >> 5) & 31, b = n >> 10;

  int th = h >> 1, tw = w >> 1;
  int i0, i1, j0, j1;
  float wh0, wh1, wv0, wv1;
  if ((h & 1) == 0) { i0 = th - 1; i1 = th;     wh0 = 0.25f; wh1 = 0.75f; }
  else              { i0 = th;     i1 = th + 1; wh0 = 0.75f; wh1 = 0.25f; }
  if ((w & 1) == 0) { j0 = tw - 1; j1 = tw;     wv0 = 0.25f; wv1 = 0.75f; }
  else              { j0 = tw;     j1 = tw + 1; wv0 = 0.75f; wv1 = 0.25f; }
  if (i0 < 0) i0 = 0; if (i1 > 15) i1 = 15;
  if (j0 < 0) j0 = 0; if (j1 > 15) j1 = 15;

  const float* q = q1 + (size_t)b * 196608 + mg * 4;
  float4 s00 = *(const float4*)&q[(i0 * 16 + j0) * 768];
  float4 s01 = *(const float4*)&q[(i0 * 16 + j1) * 768];
  float4 s10 = *(const float4*)&q[(i1 * 16 + j0) * 768];
  float4 s11 = *(const float4*)&q[(i1 * 16 + j1) * 768];

  float4 v;
  v.x = wh0 * (wv0 * s00.x + wv1 * s01.x) + wh1 * (wv0 * s10.x + wv1 * s11.x);
  v.y = wh0 * (wv0 * s00.y + wv1 * s01.y) + wh1 * (wv0 * s10.y + wv1 * s11.y);
  v.z = wh0 * (wv0 * s00.z + wv1 * s01.z) + wh1 * (wv0 * s10.z + wv1 * s11.z);
  v.w = wh0 * (wv0 * s00.w + wv1 * s01.w) + wh1 * (wv0 * s10.w + wv1 * s11.w);

  ushort4 o;
  __hip_bfloat16 t0 = __float2bfloat16(v.x); o.x = *(unsigned short*)&t0;
  __hip_bfloat16 t1 = __float2bfloat16(v.y); o.y = *(unsigned short*)&t1;
  __hip_bfloat16 t2 = __float2bfloat16(v.z); o.z = *(unsigned short*)&t2;
  __hip_bfloat16 t3 = __float2bfloat16(v.w); o.w = *(unsigned short*)&t3;
  *(ushort4*)&X[(size_t)n * 1536 + 768 + mg * 4] = o;
}

// ---------------- GEMM: out = X[8192x1536] * Wb[1536x1536]^T + bias ----------------
// 128x128 tile, BK=64, 4 waves, 16x16x32 MFMA.
// This round: (1) XOR bank-swizzle (linear LDS dest + pre-swizzled GLOBAL source,
// same XOR on ds_read side — rule #21), (2) counted-vmcnt double buffer with raw
// s_barrier (no vmcnt(0) drain in main loop), sched_barrier fences per rule #18.
#define TM 128
#define TN 128
#define TK 64
#define NT (K_TOT / TK)   // 24

__global__ __launch_bounds__(256) void gemm_kernel(
    const __hip_bfloat16* __restrict__ X,
    const __hip_bfloat16* __restrict__ Wb,
    const float* __restrict__ bias,
    float* __restrict__ out) {
  __shared__ __align__(16) __hip_bfloat16 As[2][TM * TK];
  __shared__ __align__(16) __hip_bfloat16 Bs[2][TN * TK];

  const int tid = threadIdx.x;
  const int lane = tid & 63;
  const int wave = tid >> 6;
  const int wr = wave >> 1, wc = wave & 1;

  // XCD-aware bijective swizzle: 768 blocks = 8 * 96
  int id = blockIdx.y * gridDim.x + blockIdx.x;
  int swz = (id & 7) * 96 + (id >> 3);
  const int tileN = (swz % 12) * TN;
  const int tileM = (swz / 12) * TM;

  // staging addressing (same for A and B): thread covers 4 granules G=i*256+tid,
  // row=G>>3 (row&7 == (tid>>3)&7), LDS dest LINEAR at granule G, global source
  // column granule = (tid&7) ^ (row&7)  [involution; 128B-segment-preserving]
  const int srow = tid >> 3;
  const int scol = (((tid & 7) ^ ((tid >> 3) & 7)) << 3);

  f32x4 acc[4][4] = {};

#define STAGE(buf, k0)                                                          \
  {                                                                             \
    _Pragma("unroll")                                                           \
    for (int i = 0; i < 4; ++i) {                                               \
      int row = i * 32 + srow;                                                  \
      __builtin_amdgcn_global_load_lds(                                         \
          (gptr_t)(X + (size_t)(tileM + row) * K_TOT + (k0) + scol),            \
          (sptr_t)(&As[buf][i * 2048 + tid * 8]), 16, 0, 0);                    \
    }                                                                           \
    _Pragma("unroll")                                                           \
    for (int i = 0; i < 4; ++i) {                                               \
      int row = i * 32 + srow;                                                  \
      __builtin_amdgcn_global_load_lds(                                         \
          (gptr_t)(Wb + (size_t)(tileN + row) * K_TOT + (k0) + scol),           \
          (sptr_t)(&Bs[buf][i * 2048 + tid * 8]), 16, 0, 0);                    \
    }                                                                           \
  }

#define COMPUTE(buf)                                                            \
  {                                                                             \
    const __hip_bfloat16* as = &As[buf][0];                                     \
    const __hip_bfloat16* bs = &Bs[buf][0];                                     \
    _Pragma("unroll")                                                           \
    for (int kk = 0; kk < TK; kk += 32) {                                       \
      bf16x8 afr[4], bfr[4];                                                    \
      int kq = (kk >> 3) + (lane >> 4); /* logical 16B-granule column */        \
      int pg = kq ^ (lane & 7);         /* physical (swizzled) granule */       \
      _Pragma("unroll")                                                         \
      for (int mf = 0; mf < 4; ++mf) {                                          \
        int row = wr * 64 + mf * 16 + (lane & 15);                              \
        afr[mf] = *(const bf16x8*)(as + row * TK + pg * 8);                     \
      }                                                                         \
      _Pragma("unroll")                                                         \
      for (int nf = 0; nf < 4; ++nf) {                                          \
        int col = wc * 64 + nf * 16 + (lane & 15);                              \
        bfr[nf] = *(const bf16x8*)(bs + col * TK + pg * 8);                     \
      }                                                                         \
      _Pragma("unroll")                                                         \
      for (int mf = 0; mf < 4; ++mf)                                            \
        _Pragma("unroll")                                                       \
        for (int nf = 0; nf < 4; ++nf)                                          \
          acc[mf][nf] = __builtin_amdgcn_mfma_f32_16x16x32_bf16(                \
              afr[mf], bfr[nf], acc[mf][nf], 0, 0, 0);                          \
    }                                                                           \
  }

  // prologue: stage tile 0
  STAGE(0, 0)

  for (int t = 0; t < NT - 1; ++t) {
    STAGE((t + 1) & 1, (t + 1) * TK)                     // issue next tile
    asm volatile("s_waitcnt vmcnt(8)" ::: "memory");     // wait tile t only
    __builtin_amdgcn_s_barrier();
    __builtin_amdgcn_sched_barrier(0);
    COMPUTE(t & 1)
    __builtin_amdgcn_sched_barrier(0);
    asm volatile("" ::: "memory");
    __builtin_amdgcn_s_barrier();                        // reads of buf t done
  }
  asm volatile("s_waitcnt vmcnt(0)" ::: "memory");       // last tile
  __builtin_amdgcn_s_barrier();
  __builtin_amdgcn_sched_barrier(0);
  COMPUTE((NT - 1) & 1)

  // epilogue: D layout col = lane&15, row = (lane>>4)*4 + reg   [m89-verified]
  const int colbase = tileN + wc * 64 + (lane & 15);
  const int rowbase = tileM + wr * 64 + ((lane >> 4) << 2);
#pragma unroll
  for (int mf = 0; mf < 4; ++mf) {
#pragma unroll
    for (int nf = 0; nf < 4; ++nf) {
      int col = colbase + nf * 16;
      float bv = bias[col];
#pragma unroll
      for (int r = 0; r < 4; ++r) {
        int row = rowbase + mf * 16 + r;
        out[(size_t)row * N_TOT + col] = acc[mf][nf][r] + bv;
      }
    }
  }
#undef STAGE
#undef COMPUTE
}

extern "C" void kernel_launch(void* const* d_in, const int* in_sizes, int n_in,
                              void* d_out, int out_size, void* d_ws, size_t ws_size,
                              hipStream_t stream) {
  const float* x0 = (const float*)d_in[0];
  const float* x1 = (const float*)d_in[1];
  const float* W = (const float*)d_in[2];
  const float* bias = (const float*)d_in[3];
  float* out = (float*)d_out;

  char* ws = (char*)d_ws;
  __hip_bfloat16* X = (__hip_bfloat16*)ws;                        // 25,165,824 B
  __hip_bfloat16* Wb = (__hip_bfloat16*)(ws + 25165824);          //  4,718,592 B
  float* q1 = (float*)(ws + 25165824 + 4718592);                  //  6,291,456 B

  wcvt_kernel<<<2359296 / 4 / 256, 256, 0, stream>>>(W, Wb);
  feat1_kernel<<<dim3(8, 16, 8), 256, 0, stream>>>(x1, q1);
  feat0_kernel<<<dim3(8, 32, 8), 256, 0, stream>>>(x0, X);
  feat1up_kernel<<<1572864 / 256, 256, 0, stream>>>(q1, X);

  dim3 grid(N_TOT / TN, M_TOT / TM);  // (12, 64) = 768 blocks
  gemm_kernel<<<grid, 256, 0, stream>>>(X, Wb, bias, out);
}

// Round 5
// 183.228 us; speedup vs baseline: 2.2632x; 1.0658x over previous
//
#include <hip/hip_runtime.h>
#include <hip/hip_bf16.h>

// Problem constants (INPUT_SIZE=256, IN_CH=OUT_CH=1536, B=8)
//   x0: [8, 512, 32, 32] f32;  x1: [8, 1024, 16, 16] f32
//   W : [1536, 1536] f32, b: [1536] f32;  out: [8192, 1536] f32

typedef __bf16 bf16x8 __attribute__((ext_vector_type(8)));
typedef float  f32x4  __attribute__((ext_vector_type(4)));
typedef const void __attribute__((address_space(1)))* gptr_t;
typedef void __attribute__((address_space(3)))* sptr_t;

#define M_TOT 8192
#define N_TOT 1536
#define K_TOT 1536

// ================= fused: feat1 (q1 pool, blocks 0..1023) + W->bf16 (1024..3327) =================
__global__ __launch_bounds__(256) void prep_kernel(const float* __restrict__ x1,
                                                   const float* __restrict__ W,
                                                   float* __restrict__ q1,
                                                   __hip_bfloat16* __restrict__ Wb) {
  __shared__ float T[128 * 3 * 16];
  __shared__ __align__(16) float outT[16 * 100];
  const int bid = blockIdx.x;
  const int tid = threadIdx.x;

  if (bid >= 1024) {                       // ---- wcvt part ----
    int i = ((bid - 1024) * 256 + tid) * 4;
    float4 v = *(const float4*)(W + i);
    Wb[i + 0] = __float2bfloat16(v.x);
    Wb[i + 1] = __float2bfloat16(v.y);
    Wb[i + 2] = __float2bfloat16(v.z);
    Wb[i + 3] = __float2bfloat16(v.w);
    return;
  }
  // ---- feat1 part ----
  const int cb = bid & 7, sh = (bid >> 3) & 15, b = bid >> 7;
  const float* xb = x1 + (size_t)(b * 1024 + cb * 128) * 256;

#pragma unroll
  for (int i = 0; i < 24; ++i) {
    int v = tid + i * 256;
    int c = v / 48, rem = v - c * 48;
    int y = rem >> 4, w = rem & 15;
    int gy = sh + y - 1;
    float s = 0.f;
    if (gy >= 0 && gy < 16) {
      const float* row = xb + (c * 16 + gy) * 16;
      s = row[w];
      if (w > 0)  s += row[w - 1];
      if (w < 15) s += row[w + 1];
    }
    T[v] = s;
  }
  __syncthreads();

  const int w = tid & 15, mg = tid >> 4;
#pragma unroll
  for (int k = 0; k < 6; ++k) {
    int ml = mg * 6 + k;
    int tl = ml / 3, p = ml - 3 * tl;
    const float* Tb = T + (4 * tl) * 48;
    float s;
    if (p == 0)      s = Tb[w]       + Tb[16 + w]  + Tb[32 + w]  + Tb[48 + w];
    else if (p == 1) s = Tb[64 + w]  + Tb[80 + w]  + Tb[96 + w]  + Tb[112 + w];
    else             s = Tb[128 + w] + Tb[144 + w] + Tb[160 + w] + Tb[176 + w];
    outT[w * 100 + ml] = s * (1.f / 12.f);
  }
  __syncthreads();

#pragma unroll
  for (int i = 0; i < 2; ++i) {
    int q = tid + i * 256;
    if (q < 384) {
      int nl = q / 24, qc = q - nl * 24;
      float4 v4 = *(const float4*)&outT[nl * 100 + qc * 4];
      *(float4*)&q1[(size_t)(b * 256 + sh * 16 + nl) * 768 + cb * 96 + qc * 4] = v4;
    }
  }
}

// ================= fused: feat0 (blocks 0..2047) + feat1up (2048..8191) =================
__global__ __launch_bounds__(256) void featx_kernel(const float* __restrict__ x0,
                                                    const float* __restrict__ q1,
                                                    __hip_bfloat16* __restrict__ X) {
  __shared__ float T[64 * 3 * 32];
  __shared__ __align__(16) unsigned short outT[32 * 100];
  const int bid = blockIdx.x;
  const int tid = threadIdx.x;

  if (bid >= 2048) {                       // ---- feat1up part ----
    int idx = (bid - 2048) * 256 + tid;    // 8192 * 192
    int mg = idx % 192;
    int n = idx / 192;
    int w = n & 31, h = (n >> 5) & 31, b = n >> 10;

    int th = h >> 1, tw = w >> 1;
    int i0, i1, j0, j1;
    float wh0, wh1, wv0, wv1;
    if ((h & 1) == 0) { i0 = th - 1; i1 = th;     wh0 = 0.25f; wh1 = 0.75f; }
    else              { i0 = th;     i1 = th + 1; wh0 = 0.75f; wh1 = 0.25f; }
    if ((w & 1) == 0) { j0 = tw - 1; j1 = tw;     wv0 = 0.25f; wv1 = 0.75f; }
    else              { j0 = tw;     j1 = tw + 1; wv0 = 0.75f; wv1 = 0.25f; }
    if (i0 < 0) i0 = 0; if (i1 > 15) i1 = 15;
    if (j0 < 0) j0 = 0; if (j1 > 15) j1 = 15;

    const float* q = q1 + (size_t)b * 196608 + mg * 4;
    float4 s00 = *(const float4*)&q[(i0 * 16 + j0) * 768];
    float4 s01 = *(const float4*)&q[(i0 * 16 + j1) * 768];
    float4 s10 = *(const float4*)&q[(i1 * 16 + j0) * 768];
    float4 s11 = *(const float4*)&q[(i1 * 16 + j1) * 768];

    float4 v;
    v.x = wh0 * (wv0 * s00.x + wv1 * s01.x) + wh1 * (wv0 * s10.x + wv1 * s11.x);
    v.y = wh0 * (wv0 * s00.y + wv1 * s01.y) + wh1 * (wv0 * s10.y + wv1 * s11.y);
    v.z = wh0 * (wv0 * s00.z + wv1 * s01.z) + wh1 * (wv0 * s10.z + wv1 * s11.z);
    v.w = wh0 * (wv0 * s00.w + wv1 * s01.w) + wh1 * (wv0 * s10.w + wv1 * s11.w);

    ushort4 o;
    __hip_bfloat16 t0 = __float2bfloat16(v.x); o.x = *(unsigned short*)&t0;
    __hip_bfloat16 t1 = __float2bfloat16(v.y); o.y = *(unsigned short*)&t1;
    __hip_bfloat16 t2 = __float2bfloat16(v.z); o.z = *(unsigned short*)&t2;
    __hip_bfloat16 t3 = __float2bfloat16(v.w); o.w = *(unsigned short*)&t3;
    *(ushort4*)&X[(size_t)n * 1536 + 768 + mg * 4] = o;
    return;
  }

  // ---- feat0 part ----
  const int cb = bid & 7, h = (bid >> 3) & 31, b = bid >> 8;
  const float* xb = x0 + (size_t)(b * 512 + cb * 64) * 1024;

#pragma unroll
  for (int i = 0; i < 24; ++i) {
    int v = tid + i * 256;
    int c = v / 96, rem = v - c * 96;
    int y = rem >> 5, w = rem & 31;
    int gy = h + y - 1;
    float s = 0.f;
    if (gy >= 0 && gy < 32) {
      const float* row = xb + (c * 32 + gy) * 32;
      s = row[w];
      if (w > 0)  s += row[w - 1];
      if (w < 31) s += row[w + 1];
    }
    T[v] = s;
  }
  __syncthreads();

  const int w = tid & 31, og = tid >> 5;
#pragma unroll
  for (int k = 0; k < 12; ++k) {
    int ol = og * 12 + k;
    int tl = ol / 3, p = ol - 3 * tl;
    const float* Tb = T + (2 * tl) * 96;
    float s;
    if (p == 0)      s = Tb[w]       + Tb[32 + w];
    else if (p == 1) s = Tb[64 + w]  + Tb[96 + w];
    else             s = Tb[128 + w] + Tb[160 + w];
    __hip_bfloat16 hv = __float2bfloat16(s * (1.f / 6.f));
    outT[w * 100 + ol] = *(unsigned short*)&hv;
  }
  __syncthreads();

#pragma unroll
  for (int i = 0; i < 3; ++i) {
    int q = tid + i * 256;
    int nl = q / 24, qc = q - nl * 24;
    ushort4 v4 = *(const ushort4*)&outT[nl * 100 + qc * 4];
    *(ushort4*)&X[(size_t)(b * 1024 + h * 32 + nl) * 1536 + cb * 96 + qc * 4] = v4;
  }
}

// ================= GEMM: out = X[8192x1536] * Wb[1536x1536]^T + bias =================
// 256x256 tile, BK=64, 8 waves (2M x 4N, per-wave 128x64), 128 KiB LDS dbuf.
// 4 phases per K-tile: {ds_read subtile | stage 1 half-tile -> barrier ->
// lgkmcnt(0) -> setprio(1) 16 MFMA setprio(0) -> barrier}. One counted vmcnt(2)
// per K-tile (phase 0), never 0 in main loop. T2 XOR swizzle (linear LDS dest +
// pre-swizzled global source, same XOR on read). XCD-bijective block swizzle.
#define BM 256
#define BN 256
#define BK 64
#define NT (K_TOT / BK)   // 24

__global__ __launch_bounds__(512, 2) void gemm_kernel(
    const __hip_bfloat16* __restrict__ Xg,
    const __hip_bfloat16* __restrict__ Wg,
    const float* __restrict__ bias,
    float* __restrict__ out) {
  __shared__ __align__(16) __hip_bfloat16 As[2][BM * BK];   // 32 KB each
  __shared__ __align__(16) __hip_bfloat16 Bs[2][BN * BK];

  const int tid = threadIdx.x;
  const int lane = tid & 63;
  const int wave = tid >> 6;       // 0..7
  const int wm = wave >> 2;        // 0..1  (M half)
  const int wn = wave & 3;         // 0..3  (N quarter)

  // XCD-bijective swizzle: 192 blocks = 8 XCDs x 24
  const int bid = blockIdx.x;
  const int swz = (bid & 7) * 24 + (bid >> 3);
  const int tileN = (swz % 6) * BN;
  const int tileM = (swz / 6) * BM;

  f32x4 acc[8][4] = {};
  bf16x8 bf0[4], bf1[4];

  // staging: granule g = i*512+tid (i=0..3); row=g>>3; LDS dest linear;
  // global source col-granule = (g&7) ^ (row&7)   [involution, 128B-preserving]
#define STAGE_HALF(dst, src, tb, hf, buf, k0)                                   \
  { _Pragma("unroll")                                                           \
    for (int i = (hf) * 2; i < (hf) * 2 + 2; ++i) {                             \
      int row = i * 64 + (tid >> 3);                                            \
      int cg = (tid & 7) ^ (row & 7);                                           \
      __builtin_amdgcn_global_load_lds(                                         \
          (gptr_t)((src) + (size_t)((tb) + row) * K_TOT + (k0) + cg * 8),       \
          (sptr_t)(&dst[buf][(i * 512 + tid) * 8]), 16, 0, 0);                  \
    } }

#define MFMA_CLUSTER(qm, bArr)                                                  \
  __builtin_amdgcn_s_setprio(1);                                                \
  _Pragma("unroll")                                                             \
  for (int j = 0; j < 4; ++j)                                                   \
    _Pragma("unroll")                                                           \
    for (int nf = 0; nf < 4; ++nf)                                              \
      acc[(qm) * 4 + j][nf] = __builtin_amdgcn_mfma_f32_16x16x32_bf16(          \
          af[j], bArr[nf], acc[(qm) * 4 + j][nf], 0, 0, 0);                     \
  __builtin_amdgcn_s_setprio(0);                                                \
  __builtin_amdgcn_sched_barrier(0);                                            \
  __builtin_amdgcn_s_barrier();                                                 \
  __builtin_amdgcn_sched_barrier(0);

#define READ_A(buf, qm, ks)                                                     \
  { const int pg = ((lane >> 4) + 4 * (ks)) ^ (lane & 7);                       \
    _Pragma("unroll")                                                           \
    for (int j = 0; j < 4; ++j) {                                               \
      int arow = wm * 128 + ((qm) * 4 + j) * 16 + (lane & 15);                  \
      af[j] = *(const bf16x8*)(&As[buf][arow * BK + pg * 8]);                   \
    } }

#define READ_B(buf, ks, bArr)                                                   \
  { const int pg = ((lane >> 4) + 4 * (ks)) ^ (lane & 7);                       \
    _Pragma("unroll")                                                           \
    for (int nf = 0; nf < 4; ++nf) {                                            \
      int brow = wn * 64 + nf * 16 + (lane & 15);                               \
      bArr[nf] = *(const bf16x8*)(&Bs[buf][brow * BK + pg * 8]);                \
    } }

#define WAIT_LGKM                                                               \
  asm volatile("s_waitcnt lgkmcnt(0)" ::: "memory");                            \
  __builtin_amdgcn_sched_barrier(0);

  // prologue: stage all of tile 0 into buf 0
  STAGE_HALF(Bs, Wg, tileN, 0, 0, 0)
  STAGE_HALF(Bs, Wg, tileN, 1, 0, 0)
  STAGE_HALF(As, Xg, tileM, 0, 0, 0)
  STAGE_HALF(As, Xg, tileM, 1, 0, 0)

  for (int t = 0; t < NT - 1; ++t) {
    const int buf = t & 1, nbuf = buf ^ 1;
    const int nk = (t + 1) * BK;
    bf16x8 af[4];
    // ---- phase 0 (qm0,k0): reads AFTER vmcnt->barrier (tile-t landing guarantee)
    STAGE_HALF(Bs, Wg, tileN, 0, nbuf, nk)
    asm volatile("s_waitcnt vmcnt(2)" ::: "memory");    // tile t fully landed
    __builtin_amdgcn_s_barrier();
    __builtin_amdgcn_sched_barrier(0);
    READ_A(buf, 0, 0)
    READ_B(buf, 0, bf0)
    WAIT_LGKM
    MFMA_CLUSTER(0, bf0)
    // ---- phase 1 (qm0,k1)
    READ_A(buf, 0, 1)
    READ_B(buf, 1, bf1)
    STAGE_HALF(Bs, Wg, tileN, 1, nbuf, nk)
    __builtin_amdgcn_s_barrier();
    __builtin_amdgcn_sched_barrier(0);
    WAIT_LGKM
    MFMA_CLUSTER(0, bf1)
    // ---- phase 2 (qm1,k0): B k0 reused from regs
    READ_A(buf, 1, 0)
    STAGE_HALF(As, Xg, tileM, 0, nbuf, nk)
    __builtin_amdgcn_s_barrier();
    __builtin_amdgcn_sched_barrier(0);
    WAIT_LGKM
    MFMA_CLUSTER(1, bf0)
    // ---- phase 3 (qm1,k1): B k1 reused
    READ_A(buf, 1, 1)
    STAGE_HALF(As, Xg, tileM, 1, nbuf, nk)
    __builtin_amdgcn_s_barrier();
    __builtin_amdgcn_sched_barrier(0);
    WAIT_LGKM
    MFMA_CLUSTER(1, bf1)
  }
  // ---- peeled last tile: no staging; drain all loads
  {
    const int buf = (NT - 1) & 1;
    bf16x8 af[4];
    asm volatile("s_waitcnt vmcnt(0)" ::: "memory");
    __builtin_amdgcn_s_barrier();
    __builtin_amdgcn_sched_barrier(0);
    READ_A(buf, 0, 0)
    READ_B(buf, 0, bf0)
    WAIT_LGKM
    MFMA_CLUSTER(0, bf0)
    READ_A(buf, 0, 1)
    READ_B(buf, 1, bf1)
    __builtin_amdgcn_s_barrier();
    __builtin_amdgcn_sched_barrier(0);
    WAIT_LGKM
    MFMA_CLUSTER(0, bf1)
    READ_A(buf, 1, 0)
    __builtin_amdgcn_s_barrier();
    __builtin_amdgcn_sched_barrier(0);
    WAIT_LGKM
    MFMA_CLUSTER(1, bf0)
    READ_A(buf, 1, 1)
    __builtin_amdgcn_s_barrier();
    __builtin_amdgcn_sched_barrier(0);
    WAIT_LGKM
    MFMA_CLUSTER(1, bf1)
  }

  // epilogue: D layout col = lane&15, row = (lane>>4)*4 + reg   [m89-verified]
  const int colbase = tileN + wn * 64 + (lane & 15);
  const int rowbase = tileM + wm * 128 + ((lane >> 4) << 2);
#pragma unroll
  for (int mf = 0; mf < 8; ++mf) {
#pragma unroll
    for (int nf = 0; nf < 4; ++nf) {
      int col = colbase + nf * 16;
      float bv = bias[col];
#pragma unroll
      for (int r = 0; r < 4; ++r) {
        int row = rowbase + mf * 16 + r;
        out[(size_t)row * N_TOT + col] = acc[mf][nf][r] + bv;
      }
    }
  }
#undef STAGE_HALF
#undef MFMA_CLUSTER
#undef READ_A
#undef READ_B
#undef WAIT_LGKM
}

extern "C" void kernel_launch(void* const* d_in, const int* in_sizes, int n_in,
                              void* d_out, int out_size, void* d_ws, size_t ws_size,
                              hipStream_t stream) {
  const float* x0 = (const float*)d_in[0];
  const float* x1 = (const float*)d_in[1];
  const float* W = (const float*)d_in[2];
  const float* bias = (const float*)d_in[3];
  float* out = (float*)d_out;

  char* ws = (char*)d_ws;
  __hip_bfloat16* X = (__hip_bfloat16*)ws;                        // 25,165,824 B
  __hip_bfloat16* Wb = (__hip_bfloat16*)(ws + 25165824);          //  4,718,592 B
  float* q1 = (float*)(ws + 25165824 + 4718592);                  //  6,291,456 B

  prep_kernel<<<3328, 256, 0, stream>>>(x1, W, q1, Wb);           // feat1 + wcvt
  featx_kernel<<<8192, 256, 0, stream>>>(x0, q1, X);              // feat0 + feat1up
  gemm_kernel<<<192, 512, 0, stream>>>(X, Wb, bias, out);
}

// Round 7
// 179.426 us; speedup vs baseline: 2.3111x; 1.0212x over previous
//
#include <hip/hip_runtime.h>
#include <hip/hip_bf16.h>

// Problem constants (INPUT_SIZE=256, IN_CH=OUT_CH=1536, B=8)
//   x0: [8, 512, 32, 32] f32;  x1: [8, 1024, 16, 16] f32
//   W : [1536, 1536] f32, b: [1536] f32;  out: [8192, 1536] f32

typedef __bf16 bf16x8 __attribute__((ext_vector_type(8)));
typedef float  f32x4  __attribute__((ext_vector_type(4)));
typedef const void __attribute__((address_space(1)))* gptr_t;
typedef void __attribute__((address_space(3)))* sptr_t;

#define M_TOT 8192
#define N_TOT 1536
#define K_TOT 1536

// ================= fused: feat1 (q1 pool, blocks 0..1023) + W->bf16 (1024..3327) =================
__global__ __launch_bounds__(256) void prep_kernel(const float* __restrict__ x1,
                                                   const float* __restrict__ W,
                                                   float* __restrict__ q1,
                                                   __hip_bfloat16* __restrict__ Wb) {
  __shared__ float T[128 * 3 * 16];
  __shared__ __align__(16) float outT[16 * 100];
  const int bid = blockIdx.x;
  const int tid = threadIdx.x;

  if (bid >= 1024) {                       // ---- wcvt part ----
    int i = ((bid - 1024) * 256 + tid) * 4;
    float4 v = *(const float4*)(W + i);
    Wb[i + 0] = __float2bfloat16(v.x);
    Wb[i + 1] = __float2bfloat16(v.y);
    Wb[i + 2] = __float2bfloat16(v.z);
    Wb[i + 3] = __float2bfloat16(v.w);
    return;
  }
  // ---- feat1 part ----
  const int cb = bid & 7, sh = (bid >> 3) & 15, b = bid >> 7;
  const float* xb = x1 + (size_t)(b * 1024 + cb * 128) * 256;

#pragma unroll
  for (int i = 0; i < 24; ++i) {
    int v = tid + i * 256;
    int c = v / 48, rem = v - c * 48;
    int y = rem >> 4, w = rem & 15;
    int gy = sh + y - 1;
    float s = 0.f;
    if (gy >= 0 && gy < 16) {
      const float* row = xb + (c * 16 + gy) * 16;
      s = row[w];
      if (w > 0)  s += row[w - 1];
      if (w < 15) s += row[w + 1];
    }
    T[v] = s;
  }
  __syncthreads();

  const int w = tid & 15, mg = tid >> 4;
#pragma unroll
  for (int k = 0; k < 6; ++k) {
    int ml = mg * 6 + k;
    int tl = ml / 3, p = ml - 3 * tl;
    const float* Tb = T + (4 * tl) * 48;
    float s;
    if (p == 0)      s = Tb[w]       + Tb[16 + w]  + Tb[32 + w]  + Tb[48 + w];
    else if (p == 1) s = Tb[64 + w]  + Tb[80 + w]  + Tb[96 + w]  + Tb[112 + w];
    else             s = Tb[128 + w] + Tb[144 + w] + Tb[160 + w] + Tb[176 + w];
    outT[w * 100 + ml] = s * (1.f / 12.f);
  }
  __syncthreads();

#pragma unroll
  for (int i = 0; i < 2; ++i) {
    int q = tid + i * 256;
    if (q < 384) {
      int nl = q / 24, qc = q - nl * 24;
      float4 v4 = *(const float4*)&outT[nl * 100 + qc * 4];
      *(float4*)&q1[(size_t)(b * 256 + sh * 16 + nl) * 768 + cb * 96 + qc * 4] = v4;
    }
  }
}

// ================= fused: feat0 (blocks 0..2047) + feat1up (2048..8191) =================
__global__ __launch_bounds__(256) void featx_kernel(const float* __restrict__ x0,
                                                    const float* __restrict__ q1,
                                                    __hip_bfloat16* __restrict__ X) {
  __shared__ float T[64 * 3 * 32];
  __shared__ __align__(16) unsigned short outT[32 * 100];
  const int bid = blockIdx.x;
  const int tid = threadIdx.x;

  if (bid >= 2048) {                       // ---- feat1up part ----
    int idx = (bid - 2048) * 256 + tid;    // 8192 * 192
    int mg = idx % 192;
    int n = idx / 192;
    int w = n & 31, h = (n >> 5) & 31, b = n >> 10;

    int th = h >> 1, tw = w >> 1;
    int i0, i1, j0, j1;
    float wh0, wh1, wv0, wv1;
    if ((h & 1) == 0) { i0 = th - 1; i1 = th;     wh0 = 0.25f; wh1 = 0.75f; }
    else              { i0 = th;     i1 = th + 1; wh0 = 0.75f; wh1 = 0.25f; }
    if ((w & 1) == 0) { j0 = tw - 1; j1 = tw;     wv0 = 0.25f; wv1 = 0.75f; }
    else              { j0 = tw;     j1 = tw + 1; wv0 = 0.75f; wv1 = 0.25f; }
    if (i0 < 0) i0 = 0; if (i1 > 15) i1 = 15;
    if (j0 < 0) j0 = 0; if (j1 > 15) j1 = 15;

    const float* q = q1 + (size_t)b * 196608 + mg * 4;
    float4 s00 = *(const float4*)&q[(i0 * 16 + j0) * 768];
    float4 s01 = *(const float4*)&q[(i0 * 16 + j1) * 768];
    float4 s10 = *(const float4*)&q[(i1 * 16 + j0) * 768];
    float4 s11 = *(const float4*)&q[(i1 * 16 + j1) * 768];

    float4 v;
    v.x = wh0 * (wv0 * s00.x + wv1 * s01.x) + wh1 * (wv0 * s10.x + wv1 * s11.x);
    v.y = wh0 * (wv0 * s00.y + wv1 * s01.y) + wh1 * (wv0 * s10.y + wv1 * s11.y);
    v.z = wh0 * (wv0 * s00.z + wv1 * s01.z) + wh1 * (wv0 * s10.z + wv1 * s11.z);
    v.w = wh0 * (wv0 * s00.w + wv1 * s01.w) + wh1 * (wv0 * s10.w + wv1 * s11.w);

    ushort4 o;
    __hip_bfloat16 t0 = __float2bfloat16(v.x); o.x = *(unsigned short*)&t0;
    __hip_bfloat16 t1 = __float2bfloat16(v.y); o.y = *(unsigned short*)&t1;
    __hip_bfloat16 t2 = __float2bfloat16(v.z); o.z = *(unsigned short*)&t2;
    __hip_bfloat16 t3 = __float2bfloat16(v.w); o.w = *(unsigned short*)&t3;
    *(ushort4*)&X[(size_t)n * 1536 + 768 + mg * 4] = o;
    return;
  }

  // ---- feat0 part ----
  const int cb = bid & 7, h = (bid >> 3) & 31, b = bid >> 8;
  const float* xb = x0 + (size_t)(b * 512 + cb * 64) * 1024;

#pragma unroll
  for (int i = 0; i < 24; ++i) {
    int v = tid + i * 256;
    int c = v / 96, rem = v - c * 96;
    int y = rem >> 5, w = rem & 31;
    int gy = h + y - 1;
    float s = 0.f;
    if (gy >= 0 && gy < 32) {
      const float* row = xb + (c * 32 + gy) * 32;
      s = row[w];
      if (w > 0)  s += row[w - 1];
      if (w < 31) s += row[w + 1];
    }
    T[v] = s;
  }
  __syncthreads();

  const int w = tid & 31, og = tid >> 5;
#pragma unroll
  for (int k = 0; k < 12; ++k) {
    int ol = og * 12 + k;
    int tl = ol / 3, p = ol - 3 * tl;
    const float* Tb = T + (2 * tl) * 96;
    float s;
    if (p == 0)      s = Tb[w]       + Tb[32 + w];
    else if (p == 1) s = Tb[64 + w]  + Tb[96 + w];
    else             s = Tb[128 + w] + Tb[160 + w];
    __hip_bfloat16 hv = __float2bfloat16(s * (1.f / 6.f));
    outT[w * 100 + ol] = *(unsigned short*)&hv;
  }
  __syncthreads();

#pragma unroll
  for (int i = 0; i < 3; ++i) {
    int q = tid + i * 256;
    int nl = q / 24, qc = q - nl * 24;
    ushort4 v4 = *(const ushort4*)&outT[nl * 100 + qc * 4];
    *(ushort4*)&X[(size_t)(b * 1024 + h * 32 + nl) * 1536 + cb * 96 + qc * 4] = v4;
  }
}

// ================= GEMM: out = X[8192x1536] * Wb[1536x1536]^T + bias =================
// 256x256 tile, 8 waves (2M x 4N, per-wave 128x64), K-SLICE RING:
//   slice = 32 K-cols of A and B (256x32 bf16 each = 32KB), 4-slot ring = 128KB LDS.
//   3 slices prefetched ahead, vmcnt(12) counted wait (4 loads/thread/slice),
//   never drained to 0 until the peeled tail. 2 barriers per slice.
//   Bank swizzle: physical k-granule = kgran ^ ((row>>1)&3)  -> max 2-way (free).
//   Inverse XOR applied on the GLOBAL source (linear LDS dest, rule #21).
#define SLICES 48   // K_TOT / 32

__global__ __launch_bounds__(512, 2) void gemm_kernel(
    const __hip_bfloat16* __restrict__ Xg,
    const __hip_bfloat16* __restrict__ Wg,
    const float* __restrict__ bias,
    float* __restrict__ out) {
  __shared__ __align__(16) __hip_bfloat16 ringA[4][256 * 32];   // 16KB per slot
  __shared__ __align__(16) __hip_bfloat16 ringB[4][256 * 32];

  const int tid = threadIdx.x;
  const int lane = tid & 63;
  const int wave = tid >> 6;       // 0..7
  const int wm = wave >> 2;        // 0..1
  const int wn = wave & 3;         // 0..3

  // XCD-bijective swizzle: 192 blocks = 8 XCDs x 24
  const int bid = blockIdx.x;
  const int swz = (bid & 7) * 24 + (bid >> 3);
  const int tileN = (swz % 6) * 256;
  const int tileM = (swz / 6) * 256;

  // staging: 1024 granules (16B) per operand per slice; thread covers granules
  // tid and tid+512 (row r0 and r0+128, same col). Source col-granule XOR'd.
  const int r0 = tid >> 2;
  const int sc = (tid & 3) ^ ((r0 >> 1) & 3);
  const __hip_bfloat16* srcA0 = Xg + (size_t)(tileM + r0) * K_TOT + sc * 8;
  const __hip_bfloat16* srcA1 = srcA0 + (size_t)128 * K_TOT;
  const __hip_bfloat16* srcB0 = Wg + (size_t)(tileN + r0) * K_TOT + sc * 8;
  const __hip_bfloat16* srcB1 = srcB0 + (size_t)128 * K_TOT;

  // fragment read offsets (bf16 elements), loop-invariant
  int aoff[8], boff[4];
#pragma unroll
  for (int mf = 0; mf < 8; ++mf) {
    int row = wm * 128 + mf * 16 + (lane & 15);
    int pg = (lane >> 4) ^ ((row >> 1) & 3);
    aoff[mf] = (row * 4 + pg) * 8;
  }
#pragma unroll
  for (int nf = 0; nf < 4; ++nf) {
    int row = wn * 64 + nf * 16 + (lane & 15);
    int pg = (lane >> 4) ^ ((row >> 1) & 3);
    boff[nf] = (row * 4 + pg) * 8;
  }

  f32x4 acc[8][4] = {};

#define STAGE(slot, s)                                                          \
  {                                                                             \
    __builtin_amdgcn_global_load_lds((gptr_t)(srcA0 + (s) * 32),                \
        (sptr_t)(&ringA[slot][tid * 8]), 16, 0, 0);                             \
    __builtin_amdgcn_global_load_lds((gptr_t)(srcA1 + (s) * 32),                \
        (sptr_t)(&ringA[slot][(tid + 512) * 8]), 16, 0, 0);                     \
    __builtin_amdgcn_global_load_lds((gptr_t)(srcB0 + (s) * 32),                \
        (sptr_t)(&ringB[slot][tid * 8]), 16, 0, 0);                             \
    __builtin_amdgcn_global_load_lds((gptr_t)(srcB1 + (s) * 32),                \
        (sptr_t)(&ringB[slot][(tid + 512) * 8]), 16, 0, 0);                     \
  }

#define BODY(slot)                                                              \
  {                                                                             \
    bf16x8 af[8], bf[4];                                                        \
    _Pragma("unroll")                                                           \
    for (int mf = 0; mf < 8; ++mf)                                              \
      af[mf] = *(const bf16x8*)(&ringA[slot][aoff[mf]]);                        \
    _Pragma("unroll")                                                           \
    for (int nf = 0; nf < 4; ++nf)                                              \
      bf[nf] = *(const bf16x8*)(&ringB[slot][boff[nf]]);                        \
    __builtin_amdgcn_s_setprio(1);                                              \
    _Pragma("unroll")                                                           \
    for (int mf = 0; mf < 8; ++mf)                                              \
      _Pragma("unroll")                                                         \
      for (int nf = 0; nf < 4; ++nf)                                            \
        acc[mf][nf] = __builtin_amdgcn_mfma_f32_16x16x32_bf16(                  \
            af[mf], bf[nf], acc[mf][nf], 0, 0, 0);                              \
    __builtin_amdgcn_s_setprio(0);                                              \
  }

#define OPEN(vm)                                                                \
  asm volatile("s_waitcnt vmcnt(" #vm ")" ::: "memory");                        \
  __builtin_amdgcn_s_barrier();                                                 \
  __builtin_amdgcn_sched_barrier(0);

#define CLOSE                                                                   \
  __builtin_amdgcn_sched_barrier(0);                                            \
  __builtin_amdgcn_s_barrier();                                                 \
  __builtin_amdgcn_sched_barrier(0);

  // prologue: 3 slices in flight
  STAGE(0, 0) STAGE(1, 1) STAGE(2, 2)

#pragma unroll 4
  for (int s = 0; s < SLICES - 4; ++s) {        // s = 0..43
    STAGE((s + 3) & 3, s + 3)
    OPEN(12)
    BODY(s & 3)
    CLOSE
  }
  // s = 44: stages the last slice (47)
  STAGE(3, 47)
  OPEN(12) BODY(0) CLOSE
  OPEN(8)  BODY(1) CLOSE
  OPEN(4)  BODY(2) CLOSE
  OPEN(0)  BODY(3)

  // epilogue: D layout col = lane&15, row = (lane>>4)*4 + reg   [m89-verified]
  const int colbase = tileN + wn * 64 + (lane & 15);
  const int rowbase = tileM + wm * 128 + ((lane >> 4) << 2);
#pragma unroll
  for (int mf = 0; mf < 8; ++mf) {
#pragma unroll
    for (int nf = 0; nf < 4; ++nf) {
      int col = colbase + nf * 16;
      float bv = bias[col];
#pragma unroll
      for (int r = 0; r < 4; ++r) {
        int row = rowbase + mf * 16 + r;
        out[(size_t)row * N_TOT + col] = acc[mf][nf][r] + bv;
      }
    }
  }
#undef STAGE
#undef BODY
#undef OPEN
#undef CLOSE
}

extern "C" void kernel_launch(void* const* d_in, const int* in_sizes, int n_in,
                              void* d_out, int out_size, void* d_ws, size_t ws_size,
                              hipStream_t stream) {
  const float* x0 = (const float*)d_in[0];
  const float* x1 = (const float*)d_in[1];
  const float* W = (const float*)d_in[2];
  const float* bias = (const float*)d_in[3];
  float* out = (float*)d_out;

  char* ws = (char*)d_ws;
  __hip_bfloat16* X = (__hip_bfloat16*)ws;                        // 25,165,824 B
  __hip_bfloat16* Wb = (__hip_bfloat16*)(ws + 25165824);          //  4,718,592 B
  float* q1 = (float*)(ws + 25165824 + 4718592);                  //  6,291,456 B

  prep_kernel<<<3328, 256, 0, stream>>>(x1, W, q1, Wb);           // feat1 + wcvt
  featx_kernel<<<8192, 256, 0, stream>>>(x0, q1, X);              // feat0 + feat1up
  gemm_kernel<<<192, 512, 0, stream>>>(X, Wb, bias, out);
}

// Round 8
// 177.001 us; speedup vs baseline: 2.3428x; 1.0137x over previous
//
#include <hip/hip_runtime.h>
#include <hip/hip_bf16.h>

// Problem constants (INPUT_SIZE=256, IN_CH=OUT_CH=1536, B=8)
//   x0: [8, 512, 32, 32] f32;  x1: [8, 1024, 16, 16] f32
//   W : [1536, 1536] f32, b: [1536] f32;  out: [8192, 1536] f32
//
// Factored algorithm (bilinear-upsample commutes with feature-dim GEMM):
//   X0 [8192, 768] bf16 : 6-tap pooled stencil of x0 (row-sum folding)
//   q1b [2048, 768] bf16: 12-tap pooled stencil of x1 on the 16x16 grid
//   y1 [2048, 1536] f32 = q1b @ W1^T          (W1 = W[:, 768:])
//   out = X0 @ W0^T + bias + Up_bilinear(y1)  (W0 = W[:, :768]; Up in epilogue)

typedef __bf16 bf16x8 __attribute__((ext_vector_type(8)));
typedef float  f32x4  __attribute__((ext_vector_type(4)));
typedef const void __attribute__((address_space(1)))* gptr_t;
typedef void __attribute__((address_space(3)))* sptr_t;

#define N_TOT 1536
#define KP 768            // pooled K per path

// ================= prep: feat1 (0..1023) + feat0 (1024..3071) + wcvt (3072..5375) =================
__global__ __launch_bounds__(256) void prep_kernel(const float* __restrict__ x0,
                                                   const float* __restrict__ x1,
                                                   const float* __restrict__ W,
                                                   __hip_bfloat16* __restrict__ X0,
                                                   __hip_bfloat16* __restrict__ q1b,
                                                   __hip_bfloat16* __restrict__ Wb) {
  __shared__ float T[6144];                              // 24 KB (both stencil parts)
  __shared__ __align__(16) unsigned short outT[3200];    // 6.4 KB
  const int bid = blockIdx.x;
  const int tid = threadIdx.x;

  if (bid >= 3072) {                       // ---- wcvt ----
    int i = ((bid - 3072) * 256 + tid) * 4;
    float4 v = *(const float4*)(W + i);
    Wb[i + 0] = __float2bfloat16(v.x);
    Wb[i + 1] = __float2bfloat16(v.y);
    Wb[i + 2] = __float2bfloat16(v.z);
    Wb[i + 3] = __float2bfloat16(v.w);
    return;
  }

  if (bid < 1024) {                        // ---- feat1: q1b[b][sh][sw][m] bf16 ----
    const int cb = bid & 7, sh = (bid >> 3) & 15, b = bid >> 7;
    const float* xb = x1 + (size_t)(b * 1024 + cb * 128) * 256;

#pragma unroll
    for (int i = 0; i < 24; ++i) {
      int v = tid + i * 256;
      int c = v / 48, rem = v - c * 48;
      int y = rem >> 4, w = rem & 15;
      int gy = sh + y - 1;
      float s = 0.f;
      if (gy >= 0 && gy < 16) {
        const float* row = xb + (c * 16 + gy) * 16;
        s = row[w];
        if (w > 0)  s += row[w - 1];
        if (w < 15) s += row[w + 1];
      }
      T[v] = s;
    }
    __syncthreads();

    const int w = tid & 15, mg = tid >> 4;
#pragma unroll
    for (int k = 0; k < 6; ++k) {
      int ml = mg * 6 + k;
      int tl = ml / 3, p = ml - 3 * tl;
      const float* Tb = T + (4 * tl) * 48;
      float s;
      if (p == 0)      s = Tb[w]       + Tb[16 + w]  + Tb[32 + w]  + Tb[48 + w];
      else if (p == 1) s = Tb[64 + w]  + Tb[80 + w]  + Tb[96 + w]  + Tb[112 + w];
      else             s = Tb[128 + w] + Tb[144 + w] + Tb[160 + w] + Tb[176 + w];
      __hip_bfloat16 hv = __float2bfloat16(s * (1.f / 12.f));
      outT[w * 100 + ml] = *(unsigned short*)&hv;
    }
    __syncthreads();

#pragma unroll
    for (int i = 0; i < 2; ++i) {
      int q = tid + i * 256;
      if (q < 384) {
        int nl = q / 24, qc = q - nl * 24;
        ushort4 v4 = *(const ushort4*)&outT[nl * 100 + qc * 4];
        *(ushort4*)&q1b[(size_t)(b * 256 + sh * 16 + nl) * KP + cb * 96 + qc * 4] = v4;
      }
    }
    return;
  }

  // ---- feat0: X0[b,h,w][o] bf16, stride 768 ----
  const int fb = bid - 1024;
  const int cb = fb & 7, h = (fb >> 3) & 31, b = fb >> 8;
  const float* xb = x0 + (size_t)(b * 512 + cb * 64) * 1024;

#pragma unroll
  for (int i = 0; i < 24; ++i) {
    int v = tid + i * 256;
    int c = v / 96, rem = v - c * 96;
    int y = rem >> 5, w = rem & 31;
    int gy = h + y - 1;
    float s = 0.f;
    if (gy >= 0 && gy < 32) {
      const float* row = xb + (c * 32 + gy) * 32;
      s = row[w];
      if (w > 0)  s += row[w - 1];
      if (w < 31) s += row[w + 1];
    }
    T[v] = s;
  }
  __syncthreads();

  const int w = tid & 31, og = tid >> 5;
#pragma unroll
  for (int k = 0; k < 12; ++k) {
    int ol = og * 12 + k;
    int tl = ol / 3, p = ol - 3 * tl;
    const float* Tb = T + (2 * tl) * 96;
    float s;
    if (p == 0)      s = Tb[w]       + Tb[32 + w];
    else if (p == 1) s = Tb[64 + w]  + Tb[96 + w];
    else             s = Tb[128 + w] + Tb[160 + w];
    __hip_bfloat16 hv = __float2bfloat16(s * (1.f / 6.f));
    outT[w * 100 + ol] = *(unsigned short*)&hv;
  }
  __syncthreads();

#pragma unroll
  for (int i = 0; i < 3; ++i) {
    int q = tid + i * 256;
    int nl = q / 24, qc = q - nl * 24;
    ushort4 v4 = *(const ushort4*)&outT[nl * 100 + qc * 4];
    *(ushort4*)&X0[(size_t)(b * 1024 + h * 32 + nl) * KP + cb * 96 + qc * 4] = v4;
  }
}

// ================= gemm1: y1[2048,1536] f32 = q1b[2048,768] @ (Wb[:,768:])^T =================
// 128x128 tile, BK=64, 4 waves, dbuf + counted vmcnt(8), XOR bank swizzle (R4-proven).
#define G1_NT 12   // 768/64

__global__ __launch_bounds__(256) void gemm1_kernel(
    const __hip_bfloat16* __restrict__ Ag,   // q1b, lda=768
    const __hip_bfloat16* __restrict__ Bg,   // Wb+768, ldb=1536
    float* __restrict__ Yg) {                // ldc=1536
  __shared__ __align__(16) __hip_bfloat16 As[2][128 * 64];
  __shared__ __align__(16) __hip_bfloat16 Bs[2][128 * 64];

  const int tid = threadIdx.x;
  const int lane = tid & 63;
  const int wave = tid >> 6;
  const int wr = wave >> 1, wc = wave & 1;

  // 192 blocks = 8 XCDs x 24
  int id = blockIdx.y * gridDim.x + blockIdx.x;
  int swz = (id & 7) * 24 + (id >> 3);
  const int tileN = (swz % 12) * 128;
  const int tileM = (swz / 12) * 128;

  const int srow = tid >> 3;
  const int scol = (((tid & 7) ^ ((tid >> 3) & 7)) << 3);

  f32x4 acc[4][4] = {};

#define STAGE1(buf, k0)                                                         \
  { _Pragma("unroll")                                                           \
    for (int i = 0; i < 4; ++i) {                                               \
      int row = i * 32 + srow;                                                  \
      __builtin_amdgcn_global_load_lds(                                         \
          (gptr_t)(Ag + (size_t)(tileM + row) * KP + (k0) + scol),              \
          (sptr_t)(&As[buf][i * 2048 + tid * 8]), 16, 0, 0);                    \
    }                                                                           \
    _Pragma("unroll")                                                           \
    for (int i = 0; i < 4; ++i) {                                               \
      int row = i * 32 + srow;                                                  \
      __builtin_amdgcn_global_load_lds(                                         \
          (gptr_t)(Bg + (size_t)(tileN + row) * N_TOT + (k0) + scol),           \
          (sptr_t)(&Bs[buf][i * 2048 + tid * 8]), 16, 0, 0);                    \
    } }

#define COMPUTE1(buf)                                                           \
  { const __hip_bfloat16* as = &As[buf][0];                                     \
    const __hip_bfloat16* bs = &Bs[buf][0];                                     \
    _Pragma("unroll")                                                           \
    for (int kk = 0; kk < 64; kk += 32) {                                       \
      bf16x8 afr[4], bfr[4];                                                    \
      int kq = (kk >> 3) + (lane >> 4);                                         \
      int pg = kq ^ (lane & 7);                                                 \
      _Pragma("unroll")                                                         \
      for (int mf = 0; mf < 4; ++mf) {                                          \
        int row = wr * 64 + mf * 16 + (lane & 15);                              \
        afr[mf] = *(const bf16x8*)(as + row * 64 + pg * 8);                     \
      }                                                                         \
      _Pragma("unroll")                                                         \
      for (int nf = 0; nf < 4; ++nf) {                                          \
        int col = wc * 64 + nf * 16 + (lane & 15);                              \
        bfr[nf] = *(const bf16x8*)(bs + col * 64 + pg * 8);                     \
      }                                                                         \
      _Pragma("unroll")                                                         \
      for (int mf = 0; mf < 4; ++mf)                                            \
        _Pragma("unroll")                                                       \
        for (int nf = 0; nf < 4; ++nf)                                          \
          acc[mf][nf] = __builtin_amdgcn_mfma_f32_16x16x32_bf16(                \
              afr[mf], bfr[nf], acc[mf][nf], 0, 0, 0);                          \
    } }

  STAGE1(0, 0)
  for (int t = 0; t < G1_NT - 1; ++t) {
    STAGE1((t + 1) & 1, (t + 1) * 64)
    asm volatile("s_waitcnt vmcnt(8)" ::: "memory");
    __builtin_amdgcn_s_barrier();
    __builtin_amdgcn_sched_barrier(0);
    COMPUTE1(t & 1)
    __builtin_amdgcn_sched_barrier(0);
    asm volatile("" ::: "memory");
    __builtin_amdgcn_s_barrier();
  }
  asm volatile("s_waitcnt vmcnt(0)" ::: "memory");
  __builtin_amdgcn_s_barrier();
  __builtin_amdgcn_sched_barrier(0);
  COMPUTE1((G1_NT - 1) & 1)

  const int colbase = tileN + wc * 64 + (lane & 15);
  const int rowbase = tileM + wr * 64 + ((lane >> 4) << 2);
#pragma unroll
  for (int mf = 0; mf < 4; ++mf)
#pragma unroll
    for (int nf = 0; nf < 4; ++nf) {
      int col = colbase + nf * 16;
#pragma unroll
      for (int r = 0; r < 4; ++r)
        Yg[(size_t)(rowbase + mf * 16 + r) * N_TOT + col] = acc[mf][nf][r];
    }
#undef STAGE1
#undef COMPUTE1
}

// ================= gemm0: out = X0[8192,768] @ (Wb[:,:768])^T + bias + Up(y1) =================
// 256x256 tile, 8 waves, K-slice ring (4 slots, depth-3 prefetch, vmcnt(12)).
#define SLICES 24   // 768/32

__global__ __launch_bounds__(512, 2) void gemm0_kernel(
    const __hip_bfloat16* __restrict__ Xg,   // X0, lda=768
    const __hip_bfloat16* __restrict__ Wg,   // Wb, ldb=1536 (cols 0..767 used)
    const float* __restrict__ bias,
    const float* __restrict__ y1,            // [2048,1536] f32
    float* __restrict__ out) {
  __shared__ __align__(16) __hip_bfloat16 ringA[4][256 * 32];
  __shared__ __align__(16) __hip_bfloat16 ringB[4][256 * 32];

  const int tid = threadIdx.x;
  const int lane = tid & 63;
  const int wave = tid >> 6;
  const int wm = wave >> 2;
  const int wn = wave & 3;

  const int bid = blockIdx.x;                 // 192 = 8 x 24
  const int swz = (bid & 7) * 24 + (bid >> 3);
  const int tileN = (swz % 6) * 256;
  const int tileM = (swz / 6) * 256;

  const int r0 = tid >> 2;
  const int sc = (tid & 3) ^ ((r0 >> 1) & 3);
  const __hip_bfloat16* srcA0 = Xg + (size_t)(tileM + r0) * KP + sc * 8;
  const __hip_bfloat16* srcA1 = srcA0 + (size_t)128 * KP;
  const __hip_bfloat16* srcB0 = Wg + (size_t)(tileN + r0) * N_TOT + sc * 8;
  const __hip_bfloat16* srcB1 = srcB0 + (size_t)128 * N_TOT;

  int aoff[8], boff[4];
#pragma unroll
  for (int mf = 0; mf < 8; ++mf) {
    int row = wm * 128 + mf * 16 + (lane & 15);
    int pg = (lane >> 4) ^ ((row >> 1) & 3);
    aoff[mf] = (row * 4 + pg) * 8;
  }
#pragma unroll
  for (int nf = 0; nf < 4; ++nf) {
    int row = wn * 64 + nf * 16 + (lane & 15);
    int pg = (lane >> 4) ^ ((row >> 1) & 3);
    boff[nf] = (row * 4 + pg) * 8;
  }

  f32x4 acc[8][4] = {};

#define STAGE(slot, s)                                                          \
  { __builtin_amdgcn_global_load_lds((gptr_t)(srcA0 + (s) * 32),                \
        (sptr_t)(&ringA[slot][tid * 8]), 16, 0, 0);                             \
    __builtin_amdgcn_global_load_lds((gptr_t)(srcA1 + (s) * 32),                \
        (sptr_t)(&ringA[slot][(tid + 512) * 8]), 16, 0, 0);                     \
    __builtin_amdgcn_global_load_lds((gptr_t)(srcB0 + (s) * 32),                \
        (sptr_t)(&ringB[slot][tid * 8]), 16, 0, 0);                             \
    __builtin_amdgcn_global_load_lds((gptr_t)(srcB1 + (s) * 32),                \
        (sptr_t)(&ringB[slot][(tid + 512) * 8]), 16, 0, 0); }

#define BODY(slot)                                                              \
  { bf16x8 af[8], bf[4];                                                        \
    _Pragma("unroll")                                                           \
    for (int mf = 0; mf < 8; ++mf)                                              \
      af[mf] = *(const bf16x8*)(&ringA[slot][aoff[mf]]);                        \
    _Pragma("unroll")                                                           \
    for (int nf = 0; nf < 4; ++nf)                                              \
      bf[nf] = *(const bf16x8*)(&ringB[slot][boff[nf]]);                        \
    __builtin_amdgcn_s_setprio(1);                                              \
    _Pragma("unroll")                                                           \
    for (int mf = 0; mf < 8; ++mf)                                              \
      _Pragma("unroll")                                                         \
      for (int nf = 0; nf < 4; ++nf)                                            \
        acc[mf][nf] = __builtin_amdgcn_mfma_f32_16x16x32_bf16(                  \
            af[mf], bf[nf], acc[mf][nf], 0, 0, 0);                              \
    __builtin_amdgcn_s_setprio(0); }

#define OPEN(vm)                                                                \
  asm volatile("s_waitcnt vmcnt(" #vm ")" ::: "memory");                        \
  __builtin_amdgcn_s_barrier();                                                 \
  __builtin_amdgcn_sched_barrier(0);

#define CLOSE                                                                   \
  __builtin_amdgcn_sched_barrier(0);                                            \
  __builtin_amdgcn_s_barrier();                                                 \
  __builtin_amdgcn_sched_barrier(0);

  STAGE(0, 0) STAGE(1, 1) STAGE(2, 2)

#pragma unroll 4
  for (int s = 0; s < SLICES - 4; ++s) {      // 0..19, stages 3..22
    STAGE((s + 3) & 3, s + 3)
    OPEN(12)
    BODY(s & 3)
    CLOSE
  }
  STAGE(3, SLICES - 1)                         // slice 23 -> slot 3
  OPEN(12) BODY(0) CLOSE
  OPEN(8)  BODY(1) CLOSE
  OPEN(4)  BODY(2) CLOSE
  OPEN(0)  BODY(3)

  // ---- epilogue: out = acc + bias + bilinear(y1) ----
  const int colbase = tileN + wn * 64 + (lane & 15);
  const int rowbase = tileM + wm * 128 + ((lane >> 4) << 2);
  float bv[4];
#pragma unroll
  for (int nf = 0; nf < 4; ++nf) bv[nf] = bias[colbase + nf * 16];

#pragma unroll
  for (int mf = 0; mf < 8; ++mf) {
#pragma unroll
    for (int r = 0; r < 4; ++r) {
      int row = rowbase + mf * 16 + r;
      int w = row & 31, h = (row >> 5) & 31, b = row >> 10;
      int th = h >> 1, tw = w >> 1;
      int i0, i1, j0, j1;
      float wh0, wh1, wv0, wv1;
      if ((h & 1) == 0) { i0 = th - 1; i1 = th;     wh0 = 0.25f; wh1 = 0.75f; }
      else              { i0 = th;     i1 = th + 1; wh0 = 0.75f; wh1 = 0.25f; }
      if ((w & 1) == 0) { j0 = tw - 1; j1 = tw;     wv0 = 0.25f; wv1 = 0.75f; }
      else              { j0 = tw;     j1 = tw + 1; wv0 = 0.75f; wv1 = 0.25f; }
      if (i0 < 0) i0 = 0; if (i1 > 15) i1 = 15;
      if (j0 < 0) j0 = 0; if (j1 > 15) j1 = 15;
      const float* yr0 = y1 + (size_t)(b * 256 + i0 * 16) * N_TOT;
      const float* yr1 = y1 + (size_t)(b * 256 + i1 * 16) * N_TOT;
      float w00 = wh0 * wv0, w01 = wh0 * wv1, w10 = wh1 * wv0, w11 = wh1 * wv1;
#pragma unroll
      for (int nf = 0; nf < 4; ++nf) {
        int col = colbase + nf * 16;
        float up = w00 * yr0[j0 * N_TOT + col] + w01 * yr0[j1 * N_TOT + col] +
                   w10 * yr1[j0 * N_TOT + col] + w11 * yr1[j1 * N_TOT + col];
        out[(size_t)row * N_TOT + col] = acc[mf][nf][r] + up + bv[nf];
      }
    }
  }
#undef STAGE
#undef BODY
#undef OPEN
#undef CLOSE
}

extern "C" void kernel_launch(void* const* d_in, const int* in_sizes, int n_in,
                              void* d_out, int out_size, void* d_ws, size_t ws_size,
                              hipStream_t stream) {
  const float* x0 = (const float*)d_in[0];
  const float* x1 = (const float*)d_in[1];
  const float* W = (const float*)d_in[2];
  const float* bias = (const float*)d_in[3];
  float* out = (float*)d_out;

  char* ws = (char*)d_ws;
  __hip_bfloat16* X0 = (__hip_bfloat16*)ws;                       // 12,582,912 B
  __hip_bfloat16* Wb = (__hip_bfloat16*)(ws + 12582912);          //  4,718,592 B
  __hip_bfloat16* q1b = (__hip_bfloat16*)(ws + 17301504);         //  3,145,728 B
  float* y1 = (float*)(ws + 20447232);                            // 12,582,912 B

  prep_kernel<<<5376, 256, 0, stream>>>(x0, x1, W, X0, q1b, Wb);
  gemm1_kernel<<<dim3(12, 16), 256, 0, stream>>>(q1b, Wb + 768, y1);
  gemm0_kernel<<<192, 512, 0, stream>>>(X0, Wb, bias, y1, out);
}

// Round 9
// 149.186 us; speedup vs baseline: 2.7796x; 1.1864x over previous
//
#include <hip/hip_runtime.h>
#include <hip/hip_bf16.h>

// Problem constants (INPUT_SIZE=256, IN_CH=OUT_CH=1536, B=8)
//   x0: [8, 512, 32, 32] f32;  x1: [8, 1024, 16, 16] f32
//   W : [1536, 1536] f32, b: [1536] f32;  out: [8192, 1536] f32
//
// Factored algorithm (bilinear-upsample commutes with feature-dim GEMM):
//   X0 [8192, 768] bf16 : 6-tap pooled stencil of x0 (row-sum folding)
//   q1b [2048, 768] bf16: 12-tap pooled stencil of x1 on the 16x16 grid
//   y1 [2048, 1536] bf16 = q1b @ W1^T         (W1 = W[:, 768:])
//   out = X0 @ W0^T + bias + Up_bilinear(y1)  (W0 = W[:, :768]; Up in epilogue)

typedef __bf16 bf16x8 __attribute__((ext_vector_type(8)));
typedef float  f32x4  __attribute__((ext_vector_type(4)));
typedef const void __attribute__((address_space(1)))* gptr_t;
typedef void __attribute__((address_space(3)))* sptr_t;

#define N_TOT 1536
#define KP 768            // pooled K per path

// ================= prep: feat1 (0..1023) + feat0 (1024..3071) + wcvt (3072..5375) =================
// Phase 1 (new): float4 raw rows -> LDS; T = raw[w-1]+raw[w]+raw[w+1] computed from
// registers + 2 scalar LDS neighbor reads; written in-place over raw. Phases 2/3 as before.
__global__ __launch_bounds__(256) void prep_kernel(const float* __restrict__ x0,
                                                   const float* __restrict__ x1,
                                                   const float* __restrict__ W,
                                                   __hip_bfloat16* __restrict__ X0,
                                                   __hip_bfloat16* __restrict__ q1b,
                                                   __hip_bfloat16* __restrict__ Wb) {
  __shared__ float T[6144];                              // 24 KB raw->T in place
  __shared__ __align__(16) unsigned short outT[3200];    // 6.4 KB
  const int bid = blockIdx.x;
  const int tid = threadIdx.x;

  if (bid >= 3072) {                       // ---- wcvt ----
    int i = ((bid - 3072) * 256 + tid) * 4;
    float4 v = *(const float4*)(W + i);
    Wb[i + 0] = __float2bfloat16(v.x);
    Wb[i + 1] = __float2bfloat16(v.y);
    Wb[i + 2] = __float2bfloat16(v.z);
    Wb[i + 3] = __float2bfloat16(v.w);
    return;
  }

  if (bid < 1024) {                        // ---- feat1: q1b[b][sh][sw][m] bf16 ----
    const int cb = bid & 7, sh = (bid >> 3) & 15, b = bid >> 7;
    const float* xb = x1 + (size_t)(b * 1024 + cb * 128) * 256;

    // phase 1a: raw load (float4), 128 ch x 3 rows x 4 float4
    float4 v[6];
#pragma unroll
    for (int i = 0; i < 6; ++i) {
      int f = tid + i * 256;
      int c = f / 12, rem = f - c * 12;
      int y = rem >> 2, wq = rem & 3;
      int gy = sh + y - 1;
      v[i] = make_float4(0.f, 0.f, 0.f, 0.f);
      if (gy >= 0 && gy < 16)
        v[i] = *(const float4*)(xb + (c * 16 + gy) * 16 + wq * 4);
      *(float4*)&T[f * 4] = v[i];
    }
    __syncthreads();
    // phase 1b: T from regs + LDS neighbors
    float4 t[6];
#pragma unroll
    for (int i = 0; i < 6; ++i) {
      int f = tid + i * 256;
      int wq = f & 3;   // rem&3 == f&3 since 12|4... rem = f-12c, rem&3 = f&3 (12c%4==0)
      float L = (wq == 0) ? 0.f : T[f * 4 - 1];
      float R = (wq == 3) ? 0.f : T[f * 4 + 4];
      t[i].x = L + v[i].x + v[i].y;
      t[i].y = v[i].x + v[i].y + v[i].z;
      t[i].z = v[i].y + v[i].z + v[i].w;
      t[i].w = v[i].z + v[i].w + R;
    }
    __syncthreads();
#pragma unroll
    for (int i = 0; i < 6; ++i) {
      int f = tid + i * 256;
      *(float4*)&T[f * 4] = t[i];
    }
    __syncthreads();

    // phase 2: 6 outputs/thread, 4 T-row adds each
    const int w = tid & 15, mg = tid >> 4;
#pragma unroll
    for (int k = 0; k < 6; ++k) {
      int ml = mg * 6 + k;
      int tl = ml / 3, p = ml - 3 * tl;
      const float* Tb = T + (4 * tl) * 48;
      float s;
      if (p == 0)      s = Tb[w]       + Tb[16 + w]  + Tb[32 + w]  + Tb[48 + w];
      else if (p == 1) s = Tb[64 + w]  + Tb[80 + w]  + Tb[96 + w]  + Tb[112 + w];
      else             s = Tb[128 + w] + Tb[144 + w] + Tb[160 + w] + Tb[176 + w];
      __hip_bfloat16 hv = __float2bfloat16(s * (1.f / 12.f));
      outT[w * 100 + ml] = *(unsigned short*)&hv;
    }
    __syncthreads();

#pragma unroll
    for (int i = 0; i < 2; ++i) {
      int q = tid + i * 256;
      if (q < 384) {
        int nl = q / 24, qc = q - nl * 24;
        ushort4 v4 = *(const ushort4*)&outT[nl * 100 + qc * 4];
        *(ushort4*)&q1b[(size_t)(b * 256 + sh * 16 + nl) * KP + cb * 96 + qc * 4] = v4;
      }
    }
    return;
  }

  // ---- feat0: X0[b,h,w][o] bf16, stride 768 ----
  const int fb = bid - 1024;
  const int cb = fb & 7, h = (fb >> 3) & 31, b = fb >> 8;
  const float* xb = x0 + (size_t)(b * 512 + cb * 64) * 1024;

  // phase 1a: raw load (float4), 64 ch x 3 rows x 8 float4
  float4 v[6];
#pragma unroll
  for (int i = 0; i < 6; ++i) {
    int f = tid + i * 256;
    int c = f / 24, rem = f - c * 24;
    int y = rem >> 3, wq = rem & 7;
    int gy = h + y - 1;
    v[i] = make_float4(0.f, 0.f, 0.f, 0.f);
    if (gy >= 0 && gy < 32)
      v[i] = *(const float4*)(xb + (c * 32 + gy) * 32 + wq * 4);
    *(float4*)&T[f * 4] = v[i];
  }
  __syncthreads();
  float4 t[6];
#pragma unroll
  for (int i = 0; i < 6; ++i) {
    int f = tid + i * 256;
    int wq = f & 7;   // 24c % 8 == 0 so rem&7 == f&7
    float L = (wq == 0) ? 0.f : T[f * 4 - 1];
    float R = (wq == 7) ? 0.f : T[f * 4 + 4];
    t[i].x = L + v[i].x + v[i].y;
    t[i].y = v[i].x + v[i].y + v[i].z;
    t[i].z = v[i].y + v[i].z + v[i].w;
    t[i].w = v[i].z + v[i].w + R;
  }
  __syncthreads();
#pragma unroll
  for (int i = 0; i < 6; ++i) {
    int f = tid + i * 256;
    *(float4*)&T[f * 4] = t[i];
  }
  __syncthreads();

  const int w = tid & 31, og = tid >> 5;
#pragma unroll
  for (int k = 0; k < 12; ++k) {
    int ol = og * 12 + k;
    int tl = ol / 3, p = ol - 3 * tl;
    const float* Tb = T + (2 * tl) * 96;
    float s;
    if (p == 0)      s = Tb[w]       + Tb[32 + w];
    else if (p == 1) s = Tb[64 + w]  + Tb[96 + w];
    else             s = Tb[128 + w] + Tb[160 + w];
    __hip_bfloat16 hv = __float2bfloat16(s * (1.f / 6.f));
    outT[w * 100 + ol] = *(unsigned short*)&hv;
  }
  __syncthreads();

#pragma unroll
  for (int i = 0; i < 3; ++i) {
    int q = tid + i * 256;
    int nl = q / 24, qc = q - nl * 24;
    ushort4 v4 = *(const ushort4*)&outT[nl * 100 + qc * 4];
    *(ushort4*)&X0[(size_t)(b * 1024 + h * 32 + nl) * KP + cb * 96 + qc * 4] = v4;
  }
}

// ================= gemm1: y1[2048,1536] bf16 = q1b[2048,768] @ (Wb[:,768:])^T =================
#define G1_NT 12   // 768/64

__global__ __launch_bounds__(256) void gemm1_kernel(
    const __hip_bfloat16* __restrict__ Ag,   // q1b, lda=768
    const __hip_bfloat16* __restrict__ Bg,   // Wb+768, ldb=1536
    __hip_bfloat16* __restrict__ Yg) {       // ldc=1536, bf16
  __shared__ __align__(16) __hip_bfloat16 As[2][128 * 64];
  __shared__ __align__(16) __hip_bfloat16 Bs[2][128 * 64];

  const int tid = threadIdx.x;
  const int lane = tid & 63;
  const int wave = tid >> 6;
  const int wr = wave >> 1, wc = wave & 1;

  int id = blockIdx.y * gridDim.x + blockIdx.x;
  int swz = (id & 7) * 24 + (id >> 3);
  const int tileN = (swz % 12) * 128;
  const int tileM = (swz / 12) * 128;

  const int srow = tid >> 3;
  const int scol = (((tid & 7) ^ ((tid >> 3) & 7)) << 3);

  f32x4 acc[4][4] = {};

#define STAGE1(buf, k0)                                                         \
  { _Pragma("unroll")                                                           \
    for (int i = 0; i < 4; ++i) {                                               \
      int row = i * 32 + srow;                                                  \
      __builtin_amdgcn_global_load_lds(                                         \
          (gptr_t)(Ag + (size_t)(tileM + row) * KP + (k0) + scol),              \
          (sptr_t)(&As[buf][i * 2048 + tid * 8]), 16, 0, 0);                    \
    }                                                                           \
    _Pragma("unroll")                                                           \
    for (int i = 0; i < 4; ++i) {                                               \
      int row = i * 32 + srow;                                                  \
      __builtin_amdgcn_global_load_lds(                                         \
          (gptr_t)(Bg + (size_t)(tileN + row) * N_TOT + (k0) + scol),           \
          (sptr_t)(&Bs[buf][i * 2048 + tid * 8]), 16, 0, 0);                    \
    } }

#define COMPUTE1(buf)                                                           \
  { const __hip_bfloat16* as = &As[buf][0];                                     \
    const __hip_bfloat16* bs = &Bs[buf][0];                                     \
    _Pragma("unroll")                                                           \
    for (int kk = 0; kk < 64; kk += 32) {                                       \
      bf16x8 afr[4], bfr[4];                                                    \
      int kq = (kk >> 3) + (lane >> 4);                                         \
      int pg = kq ^ (lane & 7);                                                 \
      _Pragma("unroll")                                                         \
      for (int mf = 0; mf < 4; ++mf) {                                          \
        int row = wr * 64 + mf * 16 + (lane & 15);                              \
        afr[mf] = *(const bf16x8*)(as + row * 64 + pg * 8);                     \
      }                                                                         \
      _Pragma("unroll")                                                         \
      for (int nf = 0; nf < 4; ++nf) {                                          \
        int col = wc * 64 + nf * 16 + (lane & 15);                              \
        bfr[nf] = *(const bf16x8*)(bs + col * 64 + pg * 8);                     \
      }                                                                         \
      _Pragma("unroll")                                                         \
      for (int mf = 0; mf < 4; ++mf)                                            \
        _Pragma("unroll")                                                       \
        for (int nf = 0; nf < 4; ++nf)                                          \
          acc[mf][nf] = __builtin_amdgcn_mfma_f32_16x16x32_bf16(                \
              afr[mf], bfr[nf], acc[mf][nf], 0, 0, 0);                          \
    } }

  STAGE1(0, 0)
  for (int t = 0; t < G1_NT - 1; ++t) {
    STAGE1((t + 1) & 1, (t + 1) * 64)
    asm volatile("s_waitcnt vmcnt(8)" ::: "memory");
    __builtin_amdgcn_s_barrier();
    __builtin_amdgcn_sched_barrier(0);
    COMPUTE1(t & 1)
    __builtin_amdgcn_sched_barrier(0);
    asm volatile("" ::: "memory");
    __builtin_amdgcn_s_barrier();
  }
  asm volatile("s_waitcnt vmcnt(0)" ::: "memory");
  __builtin_amdgcn_s_barrier();
  __builtin_amdgcn_sched_barrier(0);
  COMPUTE1((G1_NT - 1) & 1)

  const int colbase = tileN + wc * 64 + (lane & 15);
  const int rowbase = tileM + wr * 64 + ((lane >> 4) << 2);
#pragma unroll
  for (int mf = 0; mf < 4; ++mf)
#pragma unroll
    for (int nf = 0; nf < 4; ++nf) {
      int col = colbase + nf * 16;
#pragma unroll
      for (int r = 0; r < 4; ++r)
        Yg[(size_t)(rowbase + mf * 16 + r) * N_TOT + col] =
            __float2bfloat16(acc[mf][nf][r]);
    }
#undef STAGE1
#undef COMPUTE1
}

// ================= gemm0: out = X0[8192,768] @ (Wb[:,:768])^T + bias + Up(y1) =================
#define SLICES 24   // 768/32

__global__ __launch_bounds__(512, 2) void gemm0_kernel(
    const __hip_bfloat16* __restrict__ Xg,   // X0, lda=768
    const __hip_bfloat16* __restrict__ Wg,   // Wb, ldb=1536 (cols 0..767 used)
    const float* __restrict__ bias,
    const __hip_bfloat16* __restrict__ y1,   // [2048,1536] bf16
    float* __restrict__ out) {
  __shared__ __align__(16) __hip_bfloat16 ringA[4][256 * 32];
  __shared__ __align__(16) __hip_bfloat16 ringB[4][256 * 32];

  const int tid = threadIdx.x;
  const int lane = tid & 63;
  const int wave = tid >> 6;
  const int wm = wave >> 2;
  const int wn = wave & 3;

  const int bid = blockIdx.x;                 // 192 = 8 x 24
  const int swz = (bid & 7) * 24 + (bid >> 3);
  const int tileN = (swz % 6) * 256;
  const int tileM = (swz / 6) * 256;

  const int r0 = tid >> 2;
  const int sc = (tid & 3) ^ ((r0 >> 1) & 3);
  const __hip_bfloat16* srcA0 = Xg + (size_t)(tileM + r0) * KP + sc * 8;
  const __hip_bfloat16* srcA1 = srcA0 + (size_t)128 * KP;
  const __hip_bfloat16* srcB0 = Wg + (size_t)(tileN + r0) * N_TOT + sc * 8;
  const __hip_bfloat16* srcB1 = srcB0 + (size_t)128 * N_TOT;

  int aoff[8], boff[4];
#pragma unroll
  for (int mf = 0; mf < 8; ++mf) {
    int row = wm * 128 + mf * 16 + (lane & 15);
    int pg = (lane >> 4) ^ ((row >> 1) & 3);
    aoff[mf] = (row * 4 + pg) * 8;
  }
#pragma unroll
  for (int nf = 0; nf < 4; ++nf) {
    int row = wn * 64 + nf * 16 + (lane & 15);
    int pg = (lane >> 4) ^ ((row >> 1) & 3);
    boff[nf] = (row * 4 + pg) * 8;
  }

  f32x4 acc[8][4] = {};

#define STAGE(slot, s)                                                          \
  { __builtin_amdgcn_global_load_lds((gptr_t)(srcA0 + (s) * 32),                \
        (sptr_t)(&ringA[slot][tid * 8]), 16, 0, 0);                             \
    __builtin_amdgcn_global_load_lds((gptr_t)(srcA1 + (s) * 32),                \
        (sptr_t)(&ringA[slot][(tid + 512) * 8]), 16, 0, 0);                     \
    __builtin_amdgcn_global_load_lds((gptr_t)(srcB0 + (s) * 32),                \
        (sptr_t)(&ringB[slot][tid * 8]), 16, 0, 0);                             \
    __builtin_amdgcn_global_load_lds((gptr_t)(srcB1 + (s) * 32),                \
        (sptr_t)(&ringB[slot][(tid + 512) * 8]), 16, 0, 0); }

#define BODY(slot)                                                              \
  { bf16x8 af[8], bf[4];                                                        \
    _Pragma("unroll")                                                           \
    for (int mf = 0; mf < 8; ++mf)                                              \
      af[mf] = *(const bf16x8*)(&ringA[slot][aoff[mf]]);                        \
    _Pragma("unroll")                                                           \
    for (int nf = 0; nf < 4; ++nf)                                              \
      bf[nf] = *(const bf16x8*)(&ringB[slot][boff[nf]]);                        \
    __builtin_amdgcn_s_setprio(1);                                              \
    _Pragma("unroll")                                                           \
    for (int mf = 0; mf < 8; ++mf)                                              \
      _Pragma("unroll")                                                         \
      for (int nf = 0; nf < 4; ++nf)                                            \
        acc[mf][nf] = __builtin_amdgcn_mfma_f32_16x16x32_bf16(                  \
            af[mf], bf[nf], acc[mf][nf], 0, 0, 0);                              \
    __builtin_amdgcn_s_setprio(0); }

#define OPEN(vm)                                                                \
  asm volatile("s_waitcnt vmcnt(" #vm ")" ::: "memory");                        \
  __builtin_amdgcn_s_barrier();                                                 \
  __builtin_amdgcn_sched_barrier(0);

#define CLOSE                                                                   \
  __builtin_amdgcn_sched_barrier(0);                                            \
  __builtin_amdgcn_s_barrier();                                                 \
  __builtin_amdgcn_sched_barrier(0);

  STAGE(0, 0) STAGE(1, 1) STAGE(2, 2)

#pragma unroll 4
  for (int s = 0; s < SLICES - 4; ++s) {      // 0..19, stages 3..22
    STAGE((s + 3) & 3, s + 3)
    OPEN(12)
    BODY(s & 3)
    CLOSE
  }
  STAGE(3, SLICES - 1)                         // slice 23 -> slot 3
  OPEN(12) BODY(0) CLOSE
  OPEN(8)  BODY(1) CLOSE
  OPEN(4)  BODY(2) CLOSE
  OPEN(0)  BODY(3)

  // ---- epilogue: out = acc + bias + bilinear(y1 bf16) ----
  const int colbase = tileN + wn * 64 + (lane & 15);
  const int rowbase = tileM + wm * 128 + ((lane >> 4) << 2);
  float bv[4];
#pragma unroll
  for (int nf = 0; nf < 4; ++nf) bv[nf] = bias[colbase + nf * 16];

#pragma unroll
  for (int mf = 0; mf < 8; ++mf) {
#pragma unroll
    for (int r = 0; r < 4; ++r) {
      int row = rowbase + mf * 16 + r;
      int w = row & 31, h = (row >> 5) & 31, b = row >> 10;
      int th = h >> 1, tw = w >> 1;
      int i0, i1, j0, j1;
      float wh0, wh1, wv0, wv1;
      if ((h & 1) == 0) { i0 = th - 1; i1 = th;     wh0 = 0.25f; wh1 = 0.75f; }
      else              { i0 = th;     i1 = th + 1; wh0 = 0.75f; wh1 = 0.25f; }
      if ((w & 1) == 0) { j0 = tw - 1; j1 = tw;     wv0 = 0.25f; wv1 = 0.75f; }
      else              { j0 = tw;     j1 = tw + 1; wv0 = 0.75f; wv1 = 0.25f; }
      if (i0 < 0) i0 = 0; if (i1 > 15) i1 = 15;
      if (j0 < 0) j0 = 0; if (j1 > 15) j1 = 15;
      const __hip_bfloat16* yr0 = y1 + (size_t)(b * 256 + i0 * 16) * N_TOT;
      const __hip_bfloat16* yr1 = y1 + (size_t)(b * 256 + i1 * 16) * N_TOT;
      float w00 = wh0 * wv0, w01 = wh0 * wv1, w10 = wh1 * wv0, w11 = wh1 * wv1;
#pragma unroll
      for (int nf = 0; nf < 4; ++nf) {
        int col = colbase + nf * 16;
        float up = w00 * __bfloat162float(yr0[j0 * N_TOT + col]) +
                   w01 * __bfloat162float(yr0[j1 * N_TOT + col]) +
                   w10 * __bfloat162float(yr1[j0 * N_TOT + col]) +
                   w11 * __bfloat162float(yr1[j1 * N_TOT + col]);
        out[(size_t)row * N_TOT + col] = acc[mf][nf][r] + up + bv[nf];
      }
    }
  }
#undef STAGE
#undef BODY
#undef OPEN
#undef CLOSE
}

extern "C" void kernel_launch(void* const* d_in, const int* in_sizes, int n_in,
                              void* d_out, int out_size, void* d_ws, size_t ws_size,
                              hipStream_t stream) {
  const float* x0 = (const float*)d_in[0];
  const float* x1 = (const float*)d_in[1];
  const float* W = (const float*)d_in[2];
  const float* bias = (const float*)d_in[3];
  float* out = (float*)d_out;

  char* ws = (char*)d_ws;
  __hip_bfloat16* X0 = (__hip_bfloat16*)ws;                       // 12,582,912 B
  __hip_bfloat16* Wb = (__hip_bfloat16*)(ws + 12582912);          //  4,718,592 B
  __hip_bfloat16* q1b = (__hip_bfloat16*)(ws + 17301504);         //  3,145,728 B
  __hip_bfloat16* y1 = (__hip_bfloat16*)(ws + 20447232);          //  6,291,456 B

  prep_kernel<<<5376, 256, 0, stream>>>(x0, x1, W, X0, q1b, Wb);
  gemm1_kernel<<<dim3(12, 16), 256, 0, stream>>>(q1b, Wb + 768, y1);
  gemm0_kernel<<<192, 512, 0, stream>>>(X0, Wb, bias, y1, out);
}